// Round 15
// baseline (289.480 us; speedup 1.0000x reference)
//
#include <hip/hip_runtime.h>
#include <hip/hip_bf16.h>
#include <stdint.h>

#define NBATCH 16
#define SEQ    2048
#define DMODEL 1024
#define KSPLIT 16

// exp((s+v)/32) * 2^-4 ; s from i8 GEMM as s_int = 1024*s_raw
#define CS      0.03125f
#define KSC     3.0517578125e-5f   // CS/1024
#define NEG4LN2 2.772588722f

typedef __attribute__((ext_vector_type(8))) short short8;
typedef __attribute__((ext_vector_type(4))) float f32x4;
typedef __attribute__((ext_vector_type(4))) int i32x4;
typedef __attribute__((ext_vector_type(16))) int i32x16;

struct __align__(8) bf4 { __hip_bfloat16 h[4]; };

__device__ __forceinline__ float bf2f(short s) {
  union { uint32_t u; float f; } c;
  c.u = ((uint32_t)(uint16_t)s) << 16;
  return c.f;
}
__device__ __forceinline__ int qs8(float f, float sc) {
  int v = __float2int_rn(f * sc);
  return v > 127 ? 127 : (v < -127 ? -127 : v);
}

// async global -> LDS, 16B/lane. LDS dest = wave-uniform base + lane*16.
__device__ __forceinline__ void gload16(const void* g, void* l) {
  __builtin_amdgcn_global_load_lds(
      (const __attribute__((address_space(1))) void*)g,
      (__attribute__((address_space(3))) void*)l, 16, 0, 0);
}

#define BAR() __builtin_amdgcn_s_barrier()
#define WAIT_LGKM0()                                         \
  do {                                                       \
    asm volatile("s_waitcnt lgkmcnt(0)" ::: "memory");       \
    __builtin_amdgcn_sched_barrier(0);                       \
  } while (0)
#define WAIT_VM0()                                           \
  do {                                                       \
    asm volatile("s_waitcnt vmcnt(0)" ::: "memory");         \
  } while (0)
#define WAIT_VM2()                                           \
  do {                                                       \
    asm volatile("s_waitcnt vmcnt(2)" ::: "memory");         \
  } while (0)

// ---------------------------------------------------------------------------
// bf16 256x256 8-wave GEMM (round-9 structure). Only used for Mt8:
// OUT int8[Brow][Arow] = clamp(round(1024 * sum_e A[Arow][e]*B[Brow][e])).
template <int TP>
__global__ __launch_bounds__(512, 2)
void gemmT_kernel(const __hip_bfloat16* __restrict__ Aall,
                  const __hip_bfloat16* __restrict__ Ball,
                  uint8_t* __restrict__ O8, int ldo) {
  __shared__ __align__(16) char smem[131072];
  const int t = threadIdx.x, lane = t & 63, wid = t >> 6;
  const int wm = wid >> 2, wn = wid & 3;
  const int g = lane >> 4, l15 = lane & 15, l7 = lane & 7;

  const int at2base = blockIdx.x * TP;
  const int bt2 = blockIdx.y;
  const __hip_bfloat16* Bb = Ball + (size_t)bt2 * 256 * DMODEL;
  auto Aof = [&](int tp) { return Aall + (size_t)(at2base + tp) * 256 * DMODEL; };

  const int srl = t >> 3;
  const int sc8 = (t & 7) ^ (srl & 7);
  const int pc8[2] = {g ^ l7, (4 + g) ^ l7};

  auto stage_mat = [&](const __hip_bfloat16* gs, char* dst, int kt) {
#pragma unroll
    for (int it = 0; it < 4; ++it)
      gload16(gs + (size_t)(it * 64 + srl) * DMODEL + kt * 64 + sc8 * 8,
              dst + it * 8192 + wid * 1024);
  };

  f32x4 acc[8][4];
#pragma unroll
  for (int m = 0; m < 8; ++m)
#pragma unroll
    for (int n = 0; n < 4; ++n) acc[m][n] = (f32x4){0.f, 0.f, 0.f, 0.f};
  short8 afr[2][4], bfr[2][2][2];

#define LDA_Q(MH)                                                           \
  { _Pragma("unroll") for (int m = 0; m < 4; ++m) {                         \
      const int row = wm * 128 + ((MH) * 4 + m) * 16 + l15;                 \
      afr[0][m] = *(const short8*)(At + row * 128 + pc8[0] * 16);           \
      afr[1][m] = *(const short8*)(At + row * 128 + pc8[1] * 16);           \
    } }
#define LDB_Q(NH)                                                           \
  { _Pragma("unroll") for (int n = 0; n < 2; ++n) {                         \
      const int row = wn * 64 + ((NH) * 2 + n) * 16 + l15;                  \
      bfr[NH][0][n] = *(const short8*)(Bt + row * 128 + pc8[0] * 16);       \
      bfr[NH][1][n] = *(const short8*)(Bt + row * 128 + pc8[1] * 16);       \
    } }
#define MFMA_Q(MH, NH)                                                      \
  { __builtin_amdgcn_s_setprio(1);                                          \
    _Pragma("unroll") for (int kk = 0; kk < 2; ++kk)                        \
    _Pragma("unroll") for (int m = 0; m < 4; ++m)                           \
    _Pragma("unroll") for (int n = 0; n < 2; ++n)                           \
      acc[(MH)*4+m][(NH)*2+n] = __builtin_amdgcn_mfma_f32_16x16x32_bf16(    \
          afr[kk][m], bfr[NH][kk][n], acc[(MH)*4+m][(NH)*2+n], 0, 0, 0);    \
    __builtin_amdgcn_s_setprio(0); }

  auto EPI = [&](int at2) {
    const size_t orow0 = (size_t)bt2 * 256 + wn * 64 + l15;
    const int ocol0 = at2 * 256 + wm * 128 + g * 4;
#pragma unroll
    for (int mi = 0; mi < 8; ++mi)
#pragma unroll
      for (int ni = 0; ni < 4; ++ni) {
        uint32_t pk = 0;
#pragma unroll
        for (int j = 0; j < 4; ++j)
          pk |= (uint32_t)(qs8(acc[mi][ni][j], 1024.f) & 0xff) << (8 * j);
        *(uint32_t*)(O8 + (orow0 + ni * 16) * (size_t)ldo + ocol0 + mi * 16) = pk;
      }
#pragma unroll
    for (int m = 0; m < 8; ++m)
#pragma unroll
      for (int n = 0; n < 4; ++n) acc[m][n] = (f32x4){0.f, 0.f, 0.f, 0.f};
  };

  stage_mat(Aof(0), smem, 0);
  stage_mat(Bb, smem + 32768, 0);
  WAIT_VM0();
  BAR();

  const int NI = 16 * TP;
#pragma unroll 1
  for (int ii = 0; ii < NI; ++ii) {
    const int p = ii & 1;
    const char* At = smem + (p << 16);
    const char* Bt = smem + 32768 + (p << 16);
    char* An = smem + ((p ^ 1) << 16);
    char* Bn = smem + 32768 + ((p ^ 1) << 16);
    const int kn = (ii + 1) & 15;
    LDA_Q(0) LDB_Q(0)
    if (ii + 1 < NI) stage_mat(Aof((ii + 1) >> 4), An, kn);
    BAR(); WAIT_LGKM0(); MFMA_Q(0, 0) BAR();
    LDB_Q(1)
    if (ii + 1 < NI) stage_mat(Bb, Bn, kn);
    BAR(); WAIT_LGKM0(); MFMA_Q(0, 1) BAR();
    LDA_Q(1)
    BAR(); WAIT_LGKM0(); MFMA_Q(1, 0) BAR();
    MFMA_Q(1, 1)
    WAIT_VM0();
    if ((ii & 15) == 15) EPI(at2base + (ii >> 4));
    BAR();
  }
#undef LDA_Q
#undef LDB_Q
#undef MFMA_Q
}

// ---------------------------------------------------------------------------
// int8 256x256 tile, 16 waves (1024 thr), K-step 64B, TRIPLE-buffered LDS
// (3 x 32KB), counted vmcnt(2): stage(j+2) issued at iter j, only stage(j+1)
// drained at iter end -> one stage always in flight across the barrier (T4).
// Swizzle: 4 slots/row, phys = slot ^ ((row>>1)&3)  (4-way inherent).
// MODE 0: Y8[arow][bcol] = clamp(round(acc/1024)). grid (128/TP, 4).
// MODE 1: passA: A=x8 (k), B=Y8 (q). E8[k][q] = fp8(exp(acc*KSC + vb'[k]));
//         Zpart[cb][at2][q]. grid (8qt + 8*ktg, nb).
template <int MODE, int TP>
__global__ __launch_bounds__(1024)
void i8gemm_kernel(const uint8_t* __restrict__ Aall,
                   const uint8_t* __restrict__ Ball,
                   uint8_t* __restrict__ OUT8,
                   const float* __restrict__ vball,
                   float* __restrict__ Zpart, int b0) {
  __shared__ __align__(16) char smem[98304 + 4096];  // 3 x (16KB A + 16KB B) + red
  const int t = threadIdx.x, lane = t & 63, wid = t >> 6;  // 16 waves
  const int wm = wid >> 2, wn = wid & 3;                   // 4x4 of 64x64
  const int l31 = lane & 31, half = lane >> 5;

  int at2base, bt2, cb = 0, b = 0;
  const uint8_t *Bb, *Abatch;
  if constexpr (MODE == 0) {
    at2base = blockIdx.x * TP;
    bt2 = blockIdx.y;
    Abatch = Aall;
    Bb = Ball + (size_t)bt2 * 256 * DMODEL;
  } else {
    cb = blockIdx.y; b = b0 + cb;
    bt2 = blockIdx.x & 7;              // q-tile (256 q)
    at2base = (blockIdx.x >> 3) * TP;  // k-tile group
    Abatch = Aall + (size_t)b * SEQ * DMODEL;
    Bb = Ball + ((size_t)b * SEQ + bt2 * 256) * DMODEL;
  }
  auto Aof = [&](int tp) { return Abatch + (size_t)(at2base + tp) * 256 * DMODEL; };

  // stage: thread t -> row t>>2, source slot (t&3)^((t>>3)&3); LDS linear.
  const int srow = t >> 2;
  const int sc4 = (t & 3) ^ ((t >> 3) & 3);
  // issue one K-step stage for tile pair j into buffer bi (0..2)
  auto stage_pair = [&](const uint8_t* ga, int kt, char* base) {
    gload16(ga + (size_t)srow * DMODEL + kt * 64 + sc4 * 16, base + wid * 1024);
    gload16(Bb + (size_t)srow * DMODEL + kt * 64 + sc4 * 16,
            base + 16384 + wid * 1024);
  };

  // read phys slot for logical slot (ks*2+half) on rows with row%8 == l31%8
  int pc4[2];
#pragma unroll
  for (int ks = 0; ks < 2; ++ks)
    pc4[ks] = ((ks * 2 + half) ^ ((l31 >> 1) & 3)) * 16;

  i32x16 acci[2][2];
#pragma unroll
  for (int m = 0; m < 2; ++m)
#pragma unroll
    for (int n = 0; n < 2; ++n)
#pragma unroll
      for (int r = 0; r < 16; ++r) acci[m][n][r] = 0;

  auto EPI = [&](int at2) {
    if constexpr (MODE == 0) {
#pragma unroll
      for (int mt = 0; mt < 2; ++mt) {
        const int arow_base = at2 * 256 + wm * 64 + mt * 32 + 4 * half;
#pragma unroll
        for (int nt = 0; nt < 2; ++nt) {
          const int bcol = bt2 * 256 + wn * 64 + nt * 32 + l31;
#pragma unroll
          for (int r = 0; r < 16; ++r) {
            const int arow = arow_base + (r & 3) + 8 * (r >> 2);
            OUT8[(size_t)arow * DMODEL + bcol] =
                (uint8_t)qs8((float)acci[mt][nt][r], 9.765625e-4f);  // /1024
          }
        }
      }
    } else {
      float zc[2] = {0.f, 0.f};
#pragma unroll
      for (int mt = 0; mt < 2; ++mt) {
        const int krow_base = at2 * 256 + wm * 64 + mt * 32 + 4 * half;
        float4 vv[4];
#pragma unroll
        for (int gg = 0; gg < 4; ++gg)
          vv[gg] = *(const float4*)&vball[(size_t)b * SEQ + krow_base + 8 * gg];
#pragma unroll
        for (int nt = 0; nt < 2; ++nt) {
          const int qcol = bt2 * 256 + wn * 64 + nt * 32 + l31;
#pragma unroll
          for (int r = 0; r < 16; r += 2) {
            const float vj0 = ((const float*)&vv[r >> 2])[r & 3];
            const float vj1 = ((const float*)&vv[r >> 2])[(r + 1) & 3];
            const float e0 = __expf(fmaf((float)acci[mt][nt][r], KSC, vj0));
            const float e1 = __expf(fmaf((float)acci[mt][nt][r + 1], KSC, vj1));
            zc[nt] += e0 + e1;
            const unsigned p = __builtin_amdgcn_cvt_pk_fp8_f32(e0, e1, 0, false);
            const int krow = krow_base + (r & 3) + 8 * (r >> 2);
            uint8_t* ad = OUT8 + ((size_t)cb * SEQ + krow) * (size_t)SEQ + qcol;
            ad[0] = (uint8_t)p;
            ad[SEQ] = (uint8_t)(p >> 8);
          }
        }
      }
#pragma unroll
      for (int nt = 0; nt < 2; ++nt) {
        float v = zc[nt];
        v += __shfl_xor(v, 32);
        zc[nt] = v;
      }
      float* red = (float*)(smem + 98304);   // [4 wm][256 q]
      if (lane < 32) {
#pragma unroll
        for (int nt = 0; nt < 2; ++nt)
          red[wm * 256 + wn * 64 + nt * 32 + l31] = zc[nt];
      }
      __syncthreads();
      if (t < 256)
        Zpart[((size_t)cb * 8 + at2) * SEQ + bt2 * 256 + t] =
            red[t] + red[256 + t] + red[512 + t] + red[768 + t];
    }
#pragma unroll
    for (int m = 0; m < 2; ++m)
#pragma unroll
      for (int n = 0; n < 2; ++n)
#pragma unroll
        for (int r = 0; r < 16; ++r) acci[m][n][r] = 0;
  };

  const int NI = 16 * TP;   // 16 K-steps of 64B per k-tile
  // prologue: stage steps 0 and 1; wait step 0 (own 2 loads of step 1 remain)
  stage_pair(Aof(0), 0, smem);
  if (NI > 1) stage_pair(Aof(1 >> 4), 1, smem + 32768);
  WAIT_VM2();
  BAR();

#pragma unroll 1
  for (int j = 0; j < NI; ++j) {
    char* bcur = smem + (j % 3) * 32768;
    // issue stage(j+2) FIRST into buf (j+2)%3 (read last at iter j-1, drained)
    if (j + 2 < NI)
      stage_pair(Aof((j + 2) >> 4), (j + 2) & 15, smem + ((j + 2) % 3) * 32768);
    const int rA0 = (wm * 64 + l31) * 64, rA1 = (wm * 64 + 32 + l31) * 64;
    const int rB0 = (wn * 64 + l31) * 64, rB1 = (wn * 64 + 32 + l31) * 64;
    const char* Al = bcur;
    const char* Bl = bcur + 16384;
#pragma unroll
    for (int ks = 0; ks < 2; ++ks) {
      const i32x4 af0 = *(const i32x4*)(Al + rA0 + pc4[ks]);
      const i32x4 af1 = *(const i32x4*)(Al + rA1 + pc4[ks]);
      const i32x4 bf0 = *(const i32x4*)(Bl + rB0 + pc4[ks]);
      const i32x4 bf1 = *(const i32x4*)(Bl + rB1 + pc4[ks]);
      __builtin_amdgcn_s_setprio(1);
      acci[0][0] = __builtin_amdgcn_mfma_i32_32x32x32_i8(af0, bf0, acci[0][0], 0, 0, 0);
      acci[0][1] = __builtin_amdgcn_mfma_i32_32x32x32_i8(af0, bf1, acci[0][1], 0, 0, 0);
      acci[1][0] = __builtin_amdgcn_mfma_i32_32x32x32_i8(af1, bf0, acci[1][0], 0, 0, 0);
      acci[1][1] = __builtin_amdgcn_mfma_i32_32x32x32_i8(af1, bf1, acci[1][1], 0, 0, 0);
      __builtin_amdgcn_s_setprio(0);
    }
    WAIT_LGKM0();          // my reads of buf j%3 drained (safe to re-stage later)
    if (j + 2 < NI) { WAIT_VM2(); }  // stage(j+1) landed; (j+2) still in flight
    else           { WAIT_VM0(); }
    if ((j & 15) == 15) EPI(at2base + (j >> 4));
    BAR();
  }
}

// ---------------------------------------------------------------------------
// fp32 [DMODEL][DMODEL] -> bf16 transposed; z selects (Wq->WqT, Wk->WkT)
__global__ void transpose_cvt_kernel(const float* __restrict__ inq,
                                     const float* __restrict__ ink,
                                     __hip_bfloat16* __restrict__ outq,
                                     __hip_bfloat16* __restrict__ outk) {
  __shared__ float tile[32][33];
  const float* in = blockIdx.z ? ink : inq;
  __hip_bfloat16* outp = blockIdx.z ? outk : outq;
  const int bx = blockIdx.x, by = blockIdx.y;
  const int tx = threadIdx.x & 31, ty = threadIdx.x >> 5;
#pragma unroll
  for (int r = 0; r < 32; r += 8)
    tile[ty + r][tx] = in[(size_t)(by * 32 + ty + r) * DMODEL + bx * 32 + tx];
  __syncthreads();
#pragma unroll
  for (int r = 0; r < 32; r += 8)
    outp[(size_t)(bx * 32 + ty + r) * DMODEL + by * 32 + tx] =
        __float2bfloat16(tile[tx][ty + r]);
}

// t2[d] = sum_e Wk[e][d]*bq[e]
__global__ __launch_bounds__(256)
void prep_t2_kernel(const __hip_bfloat16* __restrict__ WkT,
                    const float* __restrict__ bq, float* __restrict__ t2) {
  const int wave = threadIdx.x >> 6, lane = threadIdx.x & 63;
  const int d = blockIdx.x * 4 + wave;
  const short8* kr = (const short8*)(WkT + (size_t)d * DMODEL);
  float a2 = 0.f;
#pragma unroll
  for (int h = 0; h < 2; ++h) {
    const short8 kv = kr[lane * 2 + h];
    const int e0 = lane * 16 + h * 8;
#pragma unroll
    for (int i = 0; i < 8; ++i) a2 += bf2f(kv[i]) * bq[e0 + i];
  }
  a2 += __shfl_down(a2, 32); a2 += __shfl_down(a2, 16); a2 += __shfl_down(a2, 8);
  a2 += __shfl_down(a2, 4);  a2 += __shfl_down(a2, 2);  a2 += __shfl_down(a2, 1);
  if (lane == 0) t2[d] = a2;
}

// fused: x -> x8i (round(32x)) + vb'
__global__ __launch_bounds__(256)
void cvtv_kernel(const float* __restrict__ x, const float* __restrict__ t2,
                 const int* __restrict__ mask,
                 uint8_t* __restrict__ x8, float* __restrict__ vb) {
  const int wave = threadIdx.x >> 6, lane = threadIdx.x & 63;
  const size_t row = (size_t)blockIdx.x * 4 + wave;
  const float* xr = x + row * DMODEL;
  float a2 = 0.f;
#pragma unroll
  for (int p = 0; p < 4; ++p) {
    const int d = p * 256 + lane * 4;
    const float4 xv = *(const float4*)(xr + d);
    const float4 tv = *(const float4*)(t2 + d);
    a2 += xv.x * tv.x + xv.y * tv.y + xv.z * tv.z + xv.w * tv.w;
    uint32_t qp = (uint32_t)(qs8(xv.x, 32.f) & 0xff) |
                  ((uint32_t)(qs8(xv.y, 32.f) & 0xff) << 8) |
                  ((uint32_t)(qs8(xv.z, 32.f) & 0xff) << 16) |
                  ((uint32_t)(qs8(xv.w, 32.f) & 0xff) << 24);
    *(uint32_t*)(x8 + row * DMODEL + d) = qp;
  }
  a2 += __shfl_down(a2, 32); a2 += __shfl_down(a2, 16); a2 += __shfl_down(a2, 8);
  a2 += __shfl_down(a2, 4);  a2 += __shfl_down(a2, 2);  a2 += __shfl_down(a2, 1);
  if (lane == 0)
    vb[row] = mask[row] ? fmaf(a2, CS, -NEG4LN2) : -1e30f;
}

// ---------------------------------------------------------------------------
// fused zinv + passB + sumw: each block computes full rZ into LDS, then
// w[k] = sum_q E8[k][q]*rZ[q] for its 128 k rows, + per-block sumw partial.
// grid (16, nb), 256 thr.
__global__ __launch_bounds__(256)
void wsolve_kernel(const uint8_t* __restrict__ E8,
                   const float* __restrict__ Zpart,
                   float* __restrict__ wout, float* __restrict__ sumwp,
                   int b0) {
  __shared__ float rz[SEQ];
  __shared__ float sred[4];
  const int t = threadIdx.x, lane = t & 63, wave = t >> 6;
  const int cb = blockIdx.y;
  for (int q = t; q < SEQ; q += 256) {
    float z = 0.f;
#pragma unroll
    for (int kt = 0; kt < 8; ++kt)
      z += Zpart[((size_t)cb * 8 + kt) * SEQ + q];
    rz[q] = (z > 0.f) ? (1.f / z) : 0.f;
  }
  __syncthreads();
  float4 rzv[4][2];
#pragma unroll
  for (int it = 0; it < 4; ++it) {
    rzv[it][0] = *(const float4*)&rz[it * 512 + lane * 8];
    rzv[it][1] = *(const float4*)&rz[it * 512 + lane * 8 + 4];
  }
  const int kbase = blockIdx.x * 128 + wave * 32;
  float wsum = 0.f;
#pragma unroll 1
  for (int r = 0; r < 32; ++r) {
    const int k = kbase + r;
    const uint2* Ep = (const uint2*)(E8 + ((size_t)cb * SEQ + k) * SEQ);
    float s = 0.f;
#pragma unroll
    for (int it = 0; it < 4; ++it) {
      const uint2 v = Ep[it * 64 + lane];
      const float* rzp = (const float*)&rzv[it][0];
      s += __builtin_amdgcn_cvt_f32_fp8(v.x, 0) * rzp[0];
      s += __builtin_amdgcn_cvt_f32_fp8(v.x, 1) * rzp[1];
      s += __builtin_amdgcn_cvt_f32_fp8(v.x, 2) * rzp[2];
      s += __builtin_amdgcn_cvt_f32_fp8(v.x, 3) * rzp[3];
      s += __builtin_amdgcn_cvt_f32_fp8(v.y, 0) * rzp[4];
      s += __builtin_amdgcn_cvt_f32_fp8(v.y, 1) * rzp[5];
      s += __builtin_amdgcn_cvt_f32_fp8(v.y, 2) * rzp[6];
      s += __builtin_amdgcn_cvt_f32_fp8(v.y, 3) * rzp[7];
    }
    s += __shfl_down(s, 32); s += __shfl_down(s, 16); s += __shfl_down(s, 8);
    s += __shfl_down(s, 4);  s += __shfl_down(s, 2);  s += __shfl_down(s, 1);
    if (lane == 0) { wout[(size_t)cb * SEQ + k] = s; wsum += s; }
  }
  if (lane == 0) sred[wave] = wsum;
  __syncthreads();
  if (t == 0)
    sumwp[(b0 + cb) * 16 + blockIdx.x] =
        sred[0] + sred[1] + sred[2] + sred[3];
}

// wxp[kq][b][d] = (1/32) * sum_{k in chunk kq} w[k] * x8[b][k][d]
__global__ __launch_bounds__(256)
void wxpart_kernel(const uint8_t* __restrict__ x8,
                   const float* __restrict__ w,
                   float* __restrict__ wxp, int b0) {
  const int cb = blockIdx.y, kq = blockIdx.z;
  const int b = b0 + cb;
  const int d4 = threadIdx.x;
  const uint8_t* xb =
      x8 + ((size_t)b * SEQ + (size_t)kq * (SEQ / KSPLIT)) * DMODEL;
  const float* wb = w + (size_t)cb * SEQ + (size_t)kq * (SEQ / KSPLIT);
  float a0 = 0.f, a1 = 0.f, a2 = 0.f, a3 = 0.f;
#pragma unroll 4
  for (int k = 0; k < SEQ / KSPLIT; ++k) {
    const float wk = wb[k];
    const uint32_t pv = *(const uint32_t*)(xb + (size_t)k * DMODEL + d4 * 4);
    a0 += wk * (float)(int8_t)(pv & 0xff);
    a1 += wk * (float)(int8_t)((pv >> 8) & 0xff);
    a2 += wk * (float)(int8_t)((pv >> 16) & 0xff);
    a3 += wk * (float)(int8_t)(pv >> 24);
  }
  float4* o = (float4*)&wxp[((size_t)kq * NBATCH + b) * DMODEL + d4 * 4];
  *o = make_float4(a0 * 0.03125f, a1 * 0.03125f, a2 * 0.03125f, a3 * 0.03125f);
}

// out[b][e] = ( sum_d (sum_kq wxp) * Wv[e][d] + sumw[b]*bv[e] ) / SEQ
__global__ void final_kernel(const float* __restrict__ wxp,
                             const float* __restrict__ sumwp,
                             const float* __restrict__ Wv,
                             const float* __restrict__ bv,
                             float* __restrict__ out) {
  const int b = blockIdx.y, eg = blockIdx.x;
  const int wave = threadIdx.x >> 6, lane = threadIdx.x & 63;
  const int e = eg * 4 + wave;
  float acc = 0.f;
  for (int d = lane; d < DMODEL; d += 64) {
    float wx = 0.f;
#pragma unroll
    for (int kq = 0; kq < KSPLIT; ++kq)
      wx += wxp[((size_t)kq * NBATCH + b) * DMODEL + d];
    acc += wx * Wv[(size_t)e * DMODEL + d];
  }
  acc += __shfl_down(acc, 32); acc += __shfl_down(acc, 16);
  acc += __shfl_down(acc, 8);  acc += __shfl_down(acc, 4);
  acc += __shfl_down(acc, 2);  acc += __shfl_down(acc, 1);
  if (lane == 0) {
    float sw = 0.f;
#pragma unroll
    for (int i = 0; i < 16; ++i) sw += sumwp[b * 16 + i];
    out[(size_t)b * DMODEL + e] = (acc + sw * bv[e]) * (1.f / (float)SEQ);
  }
}

// ---------------------------------------------------------------------------
extern "C" void kernel_launch(void* const* d_in, const int* in_sizes, int n_in,
                              void* d_out, int out_size, void* d_ws, size_t ws_size,
                              hipStream_t stream) {
  const float* x  = (const float*)d_in[0];
  const int* mask = (const int*)d_in[1];
  const float* Wq = (const float*)d_in[2];
  const float* bq = (const float*)d_in[3];
  const float* Wk = (const float*)d_in[4];
  const float* bk = (const float*)d_in[5];
  const float* Wv = (const float*)d_in[6];
  const float* bv = (const float*)d_in[7];
  float* out = (float*)d_out;
  (void)bk;

  char* ws = (char*)d_ws;
  size_t off = 0;
  auto alloc = [&](size_t bytes) -> void* {
    void* p = ws + off;
    off += (bytes + 255) & ~(size_t)255;
    return p;
  };
  // ---- persistent ----
  uint8_t* Mt8 = (uint8_t*)alloc((size_t)DMODEL * DMODEL);
  __hip_bfloat16* WqT_bf = (__hip_bfloat16*)alloc((size_t)DMODEL * DMODEL * 2);
  __hip_bfloat16* WkT_bf = (__hip_bfloat16*)alloc((size_t)DMODEL * DMODEL * 2);
  float* wxp   = (float*)alloc((size_t)KSPLIT * NBATCH * DMODEL * 4);
  float* sumwp = (float*)alloc((size_t)NBATCH * 16 * 4);
  float* t2    = (float*)alloc((size_t)DMODEL * 4);
  uint8_t* x8i = (uint8_t*)alloc((size_t)NBATCH * SEQ * DMODEL);
  uint8_t* Y8i = (uint8_t*)alloc((size_t)NBATCH * SEQ * DMODEL);
  float* vb = (float*)alloc((size_t)NBATCH * SEQ * 4);
  const size_t fixed = off;

  // ---- per-chunk ----
  const size_t per_batch = (size_t)SEQ * SEQ      // E (fp8)
                         + (size_t)8 * SEQ * 4    // Zpart
                         + (size_t)SEQ * 4 + 8 * 256;
  long avail = (long)ws_size - (long)fixed;
  int NB = (int)(avail / (long)per_batch);
  if (NB < 1) NB = 1;
  if (NB > NBATCH) NB = NBATCH;
  while (NBATCH % NB) --NB;
  uint8_t* Ebuf = (uint8_t*)alloc((size_t)NB * SEQ * SEQ);
  float* Zpart = (float*)alloc((size_t)NB * 8 * SEQ * 4);
  float* wbuf  = (float*)alloc((size_t)NB * SEQ * 4);

  // ---- prep ----
  transpose_cvt_kernel<<<dim3(32, 32, 2), dim3(256), 0, stream>>>(
      Wq, Wk, WqT_bf, WkT_bf);
  // Mt8[d'][d] = round(1024 * sum_e WkT[d'][e]*WqT[d][e])
  gemmT_kernel<1><<<dim3(4, 4), dim3(512), 0, stream>>>(
      WqT_bf, WkT_bf, Mt8, DMODEL);
  prep_t2_kernel<<<dim3(256), dim3(256), 0, stream>>>(WkT_bf, bq, t2);
  cvtv_kernel<<<dim3(NBATCH * SEQ / 4), dim3(256), 0, stream>>>(
      x, t2, mask, x8i, vb);
  // Y8i = round( (x8 . Mt8) / 1024 ); 128 A-tiles, TP=2 -> 64 x 4 = 256 blocks
  i8gemm_kernel<0, 2><<<dim3(64, DMODEL / 256), dim3(1024), 0, stream>>>(
      x8i, Mt8, Y8i, nullptr, nullptr, 0);

  for (int b0 = 0; b0 < NBATCH; b0 += NB) {
    const int nb = NB;
    // passA: 8 qt x 2 ktg (TP=4) -> 16 x nb blocks
    i8gemm_kernel<1, 4><<<dim3(16, nb), dim3(1024), 0, stream>>>(
        x8i, Y8i, Ebuf, vb, Zpart, b0);
    wsolve_kernel<<<dim3(16, nb), dim3(256), 0, stream>>>(
        Ebuf, Zpart, wbuf, sumwp, b0);
    wxpart_kernel<<<dim3(1, nb, KSPLIT), dim3(256), 0, stream>>>(
        x8i, wbuf, wxp, b0);
  }
  final_kernel<<<dim3(DMODEL / 4, NBATCH), dim3(256), 0, stream>>>(
      wxp, sumwp, Wv, bv, out);
}

// Round 16
// 279.956 us; speedup vs baseline: 1.0340x; 1.0340x over previous
//
#include <hip/hip_runtime.h>
#include <hip/hip_bf16.h>
#include <stdint.h>

#define NBATCH 16
#define SEQ    2048
#define DMODEL 1024
#define KSPLIT 16

// exp((s+v)/32) * 2^-4 ; s from i8 GEMM as s_int = 1024*s_raw
#define CS      0.03125f
#define KSC     3.0517578125e-5f   // CS/1024
#define NEG4LN2 2.772588722f

typedef __attribute__((ext_vector_type(8))) short short8;
typedef __attribute__((ext_vector_type(4))) float f32x4;
typedef __attribute__((ext_vector_type(4))) int i32x4;
typedef __attribute__((ext_vector_type(16))) int i32x16;

struct __align__(8) bf4 { __hip_bfloat16 h[4]; };

__device__ __forceinline__ float bf2f(short s) {
  union { uint32_t u; float f; } c;
  c.u = ((uint32_t)(uint16_t)s) << 16;
  return c.f;
}
__device__ __forceinline__ int qs8(float f, float sc) {
  int v = __float2int_rn(f * sc);
  return v > 127 ? 127 : (v < -127 ? -127 : v);
}

// async global -> LDS, 16B/lane. LDS dest = wave-uniform base + lane*16.
__device__ __forceinline__ void gload16(const void* g, void* l) {
  __builtin_amdgcn_global_load_lds(
      (const __attribute__((address_space(1))) void*)g,
      (__attribute__((address_space(3))) void*)l, 16, 0, 0);
}

#define BAR() __builtin_amdgcn_s_barrier()
#define WAIT_LGKM0()                                         \
  do {                                                       \
    asm volatile("s_waitcnt lgkmcnt(0)" ::: "memory");       \
    __builtin_amdgcn_sched_barrier(0);                       \
  } while (0)
#define WAIT_VM0()                                           \
  do {                                                       \
    asm volatile("s_waitcnt vmcnt(0)" ::: "memory");         \
  } while (0)

// ---------------------------------------------------------------------------
// bf16 256x256 8-wave GEMM (round-9 structure). Only used for Mt8:
// OUT int8[Brow][Arow] = clamp(round(1024 * sum_e A[Arow][e]*B[Brow][e])).
template <int TP>
__global__ __launch_bounds__(512, 2)
void gemmT_kernel(const __hip_bfloat16* __restrict__ Aall,
                  const __hip_bfloat16* __restrict__ Ball,
                  uint8_t* __restrict__ O8, int ldo) {
  __shared__ __align__(16) char smem[131072];
  const int t = threadIdx.x, lane = t & 63, wid = t >> 6;
  const int wm = wid >> 2, wn = wid & 3;
  const int g = lane >> 4, l15 = lane & 15, l7 = lane & 7;

  const int at2base = blockIdx.x * TP;
  const int bt2 = blockIdx.y;
  const __hip_bfloat16* Bb = Ball + (size_t)bt2 * 256 * DMODEL;
  auto Aof = [&](int tp) { return Aall + (size_t)(at2base + tp) * 256 * DMODEL; };

  const int srl = t >> 3;
  const int sc8 = (t & 7) ^ (srl & 7);
  const int pc8[2] = {g ^ l7, (4 + g) ^ l7};

  auto stage_mat = [&](const __hip_bfloat16* gs, char* dst, int kt) {
#pragma unroll
    for (int it = 0; it < 4; ++it)
      gload16(gs + (size_t)(it * 64 + srl) * DMODEL + kt * 64 + sc8 * 8,
              dst + it * 8192 + wid * 1024);
  };

  f32x4 acc[8][4];
#pragma unroll
  for (int m = 0; m < 8; ++m)
#pragma unroll
    for (int n = 0; n < 4; ++n) acc[m][n] = (f32x4){0.f, 0.f, 0.f, 0.f};
  short8 afr[2][4], bfr[2][2][2];

#define LDA_Q(MH)                                                           \
  { _Pragma("unroll") for (int m = 0; m < 4; ++m) {                         \
      const int row = wm * 128 + ((MH) * 4 + m) * 16 + l15;                 \
      afr[0][m] = *(const short8*)(At + row * 128 + pc8[0] * 16);           \
      afr[1][m] = *(const short8*)(At + row * 128 + pc8[1] * 16);           \
    } }
#define LDB_Q(NH)                                                           \
  { _Pragma("unroll") for (int n = 0; n < 2; ++n) {                         \
      const int row = wn * 64 + ((NH) * 2 + n) * 16 + l15;                  \
      bfr[NH][0][n] = *(const short8*)(Bt + row * 128 + pc8[0] * 16);       \
      bfr[NH][1][n] = *(const short8*)(Bt + row * 128 + pc8[1] * 16);       \
    } }
#define MFMA_Q(MH, NH)                                                      \
  { __builtin_amdgcn_s_setprio(1);                                          \
    _Pragma("unroll") for (int kk = 0; kk < 2; ++kk)                        \
    _Pragma("unroll") for (int m = 0; m < 4; ++m)                           \
    _Pragma("unroll") for (int n = 0; n < 2; ++n)                           \
      acc[(MH)*4+m][(NH)*2+n] = __builtin_amdgcn_mfma_f32_16x16x32_bf16(    \
          afr[kk][m], bfr[NH][kk][n], acc[(MH)*4+m][(NH)*2+n], 0, 0, 0);    \
    __builtin_amdgcn_s_setprio(0); }

  auto EPI = [&](int at2) {
    const size_t orow0 = (size_t)bt2 * 256 + wn * 64 + l15;
    const int ocol0 = at2 * 256 + wm * 128 + g * 4;
#pragma unroll
    for (int mi = 0; mi < 8; ++mi)
#pragma unroll
      for (int ni = 0; ni < 4; ++ni) {
        uint32_t pk = 0;
#pragma unroll
        for (int j = 0; j < 4; ++j)
          pk |= (uint32_t)(qs8(acc[mi][ni][j], 1024.f) & 0xff) << (8 * j);
        *(uint32_t*)(O8 + (orow0 + ni * 16) * (size_t)ldo + ocol0 + mi * 16) = pk;
      }
#pragma unroll
    for (int m = 0; m < 8; ++m)
#pragma unroll
      for (int n = 0; n < 4; ++n) acc[m][n] = (f32x4){0.f, 0.f, 0.f, 0.f};
  };

  stage_mat(Aof(0), smem, 0);
  stage_mat(Bb, smem + 32768, 0);
  WAIT_VM0();
  BAR();

  const int NI = 16 * TP;
#pragma unroll 1
  for (int ii = 0; ii < NI; ++ii) {
    const int p = ii & 1;
    const char* At = smem + (p << 16);
    const char* Bt = smem + 32768 + (p << 16);
    char* An = smem + ((p ^ 1) << 16);
    char* Bn = smem + 32768 + ((p ^ 1) << 16);
    const int kn = (ii + 1) & 15;
    LDA_Q(0) LDB_Q(0)
    if (ii + 1 < NI) stage_mat(Aof((ii + 1) >> 4), An, kn);
    BAR(); WAIT_LGKM0(); MFMA_Q(0, 0) BAR();
    LDB_Q(1)
    if (ii + 1 < NI) stage_mat(Bb, Bn, kn);
    BAR(); WAIT_LGKM0(); MFMA_Q(0, 1) BAR();
    LDA_Q(1)
    BAR(); WAIT_LGKM0(); MFMA_Q(1, 0) BAR();
    MFMA_Q(1, 1)
    WAIT_VM0();
    if ((ii & 15) == 15) EPI(at2base + (ii >> 4));
    BAR();
  }
#undef LDA_Q
#undef LDB_Q
#undef MFMA_Q
}

// ---------------------------------------------------------------------------
// int8 256x256 tile over 16 waves (1024 thr), K-step 128B, dbuf 128KiB LDS,
// mfma_i32_32x32x32_i8 (round-14 schedule, the 98-us best).
// MODE 0: Y8[arow][bcol] = clamp(round(acc/1024)). grid (128/TP, 4).
// MODE 1: passA. grid (2*nb, 8): bx = cb*2+ktg (FAST -> blocks sharing the
//         A k-panel get ids == same residue mod 8 -> same XCD -> L2 reuse),
//         by = qt. E8[k][q] = fp8(exp(acc*KSC + vb'[k])); Zpart[cb][at2][q].
template <int MODE, int TP>
__global__ __launch_bounds__(1024)
void i8gemm_kernel(const uint8_t* __restrict__ Aall,
                   const uint8_t* __restrict__ Ball,
                   uint8_t* __restrict__ OUT8,
                   const float* __restrict__ vball,
                   float* __restrict__ Zpart, int b0) {
  __shared__ __align__(16) char smem[131072 + 4096];
  const int t = threadIdx.x, lane = t & 63, wid = t >> 6;  // 16 waves
  const int wm = wid >> 2, wn = wid & 3;                   // 4x4 of 64x64
  const int l31 = lane & 31, half = lane >> 5, l7 = lane & 7;

  int at2base, bt2, cb = 0, b = 0;
  const uint8_t *Bb, *Abatch;
  if constexpr (MODE == 0) {
    at2base = blockIdx.x * TP;
    bt2 = blockIdx.y;
    Abatch = Aall;
    Bb = Ball + (size_t)bt2 * 256 * DMODEL;
  } else {
    cb = blockIdx.x >> 1; b = b0 + cb;       // (cb,ktg) in FAST dim
    at2base = (blockIdx.x & 1) * TP;         // ktg -> k-tile group
    bt2 = blockIdx.y;                        // q-tile (256 q), SLOW dim
    Abatch = Aall + (size_t)b * SEQ * DMODEL;
    Bb = Ball + ((size_t)b * SEQ + bt2 * 256) * DMODEL;
  }
  auto Aof = [&](int tp) { return Abatch + (size_t)(at2base + tp) * 256 * DMODEL; };

  const int sc8 = (t & 7) ^ ((t >> 3) & 7);   // pre-swizzled source 16B-slot
  int pcI[4];
#pragma unroll
  for (int ks = 0; ks < 4; ++ks) pcI[ks] = ((ks * 2 + half) ^ l7) * 16;

  // 32KB tile: [256 rows][8 slots of 16B], slot XOR row&7. 1024thr x 2 loads.
  auto stage_mat = [&](const uint8_t* gs, char* dst, int kt) {
#pragma unroll
    for (int it = 0; it < 2; ++it)
      gload16(gs + (size_t)(it * 128 + (t >> 3)) * DMODEL + kt * 128 + sc8 * 16,
              dst + it * 16384 + wid * 1024);
  };

  i32x16 acci[2][2];
#pragma unroll
  for (int m = 0; m < 2; ++m)
#pragma unroll
    for (int n = 0; n < 2; ++n)
#pragma unroll
      for (int r = 0; r < 16; ++r) acci[m][n][r] = 0;

  auto EPI = [&](int at2) {
    if constexpr (MODE == 0) {
#pragma unroll
      for (int mt = 0; mt < 2; ++mt) {
        const int arow_base = at2 * 256 + wm * 64 + mt * 32 + 4 * half;
#pragma unroll
        for (int nt = 0; nt < 2; ++nt) {
          const int bcol = bt2 * 256 + wn * 64 + nt * 32 + l31;
#pragma unroll
          for (int r = 0; r < 16; ++r) {
            const int arow = arow_base + (r & 3) + 8 * (r >> 2);
            OUT8[(size_t)arow * DMODEL + bcol] =
                (uint8_t)qs8((float)acci[mt][nt][r], 9.765625e-4f);  // /1024
          }
        }
      }
    } else {
      float zc[2] = {0.f, 0.f};
#pragma unroll
      for (int mt = 0; mt < 2; ++mt) {
        const int krow_base = at2 * 256 + wm * 64 + mt * 32 + 4 * half;
        float4 vv[4];
#pragma unroll
        for (int gg = 0; gg < 4; ++gg)
          vv[gg] = *(const float4*)&vball[(size_t)b * SEQ + krow_base + 8 * gg];
#pragma unroll
        for (int nt = 0; nt < 2; ++nt) {
          const int qcol = bt2 * 256 + wn * 64 + nt * 32 + l31;
#pragma unroll
          for (int r = 0; r < 16; r += 2) {
            const float vj0 = ((const float*)&vv[r >> 2])[r & 3];
            const float vj1 = ((const float*)&vv[r >> 2])[(r + 1) & 3];
            const float e0 = __expf(fmaf((float)acci[mt][nt][r], KSC, vj0));
            const float e1 = __expf(fmaf((float)acci[mt][nt][r + 1], KSC, vj1));
            zc[nt] += e0 + e1;
            const unsigned p = __builtin_amdgcn_cvt_pk_fp8_f32(e0, e1, 0, false);
            const int krow = krow_base + (r & 3) + 8 * (r >> 2);
            uint8_t* ad = OUT8 + ((size_t)cb * SEQ + krow) * (size_t)SEQ + qcol;
            ad[0] = (uint8_t)p;
            ad[SEQ] = (uint8_t)(p >> 8);
          }
        }
      }
#pragma unroll
      for (int nt = 0; nt < 2; ++nt) {
        float v = zc[nt];
        v += __shfl_xor(v, 32);
        zc[nt] = v;
      }
      float* red = (float*)(smem + 131072);   // [4 wm][256 q]
      if (lane < 32) {
#pragma unroll
        for (int nt = 0; nt < 2; ++nt)
          red[wm * 256 + wn * 64 + nt * 32 + l31] = zc[nt];
      }
      __syncthreads();
      if (t < 256)
        Zpart[((size_t)cb * 8 + at2) * SEQ + bt2 * 256 + t] =
            red[t] + red[256 + t] + red[512 + t] + red[768 + t];
    }
#pragma unroll
    for (int m = 0; m < 2; ++m)
#pragma unroll
      for (int n = 0; n < 2; ++n)
#pragma unroll
        for (int r = 0; r < 16; ++r) acci[m][n][r] = 0;
  };

  // prologue: tile 0 -> buf0
  stage_mat(Aof(0), smem, 0);
  stage_mat(Bb, smem + 32768, 0);
  WAIT_VM0();
  BAR();

  const int NI = 8 * TP;   // 8 K-steps of 128B per k-tile
#pragma unroll 1
  for (int ii = 0; ii < NI; ++ii) {
    const int p = ii & 1;
    const char* Al = smem + (p << 16);
    const char* Bl = smem + 32768 + (p << 16);
    // issue next-tile stage FIRST (max issue->drain distance)
    if (ii + 1 < NI) {
      stage_mat(Aof((ii + 1) >> 3), smem + ((p ^ 1) << 16), (ii + 1) & 7);
      stage_mat(Bb, smem + 32768 + ((p ^ 1) << 16), (ii + 1) & 7);
    }
    const int rA0 = (wm * 64 + l31) * 128, rA1 = (wm * 64 + 32 + l31) * 128;
    const int rB0 = (wn * 64 + l31) * 128, rB1 = (wn * 64 + 32 + l31) * 128;
#pragma unroll
    for (int ks = 0; ks < 4; ++ks) {
      const i32x4 af0 = *(const i32x4*)(Al + rA0 + pcI[ks]);
      const i32x4 af1 = *(const i32x4*)(Al + rA1 + pcI[ks]);
      const i32x4 bf0 = *(const i32x4*)(Bl + rB0 + pcI[ks]);
      const i32x4 bf1 = *(const i32x4*)(Bl + rB1 + pcI[ks]);
      __builtin_amdgcn_s_setprio(1);
      acci[0][0] = __builtin_amdgcn_mfma_i32_32x32x32_i8(af0, bf0, acci[0][0], 0, 0, 0);
      acci[0][1] = __builtin_amdgcn_mfma_i32_32x32x32_i8(af0, bf1, acci[0][1], 0, 0, 0);
      acci[1][0] = __builtin_amdgcn_mfma_i32_32x32x32_i8(af1, bf0, acci[1][0], 0, 0, 0);
      acci[1][1] = __builtin_amdgcn_mfma_i32_32x32x32_i8(af1, bf1, acci[1][1], 0, 0, 0);
      __builtin_amdgcn_s_setprio(0);
    }
    WAIT_LGKM0();   // all my ds-reads of buf p drained before crossing barrier
    WAIT_VM0();     // next tile landed
    if ((ii & 7) == 7) EPI(at2base + (ii >> 3));
    BAR();
  }
}

// ---------------------------------------------------------------------------
// fp32 [DMODEL][DMODEL] -> bf16 transposed; z selects (Wq->WqT, Wk->WkT)
__global__ void transpose_cvt_kernel(const float* __restrict__ inq,
                                     const float* __restrict__ ink,
                                     __hip_bfloat16* __restrict__ outq,
                                     __hip_bfloat16* __restrict__ outk) {
  __shared__ float tile[32][33];
  const float* in = blockIdx.z ? ink : inq;
  __hip_bfloat16* outp = blockIdx.z ? outk : outq;
  const int bx = blockIdx.x, by = blockIdx.y;
  const int tx = threadIdx.x & 31, ty = threadIdx.x >> 5;
#pragma unroll
  for (int r = 0; r < 32; r += 8)
    tile[ty + r][tx] = in[(size_t)(by * 32 + ty + r) * DMODEL + bx * 32 + tx];
  __syncthreads();
#pragma unroll
  for (int r = 0; r < 32; r += 8)
    outp[(size_t)(bx * 32 + ty + r) * DMODEL + by * 32 + tx] =
        __float2bfloat16(tile[tx][ty + r]);
}

// t2[d] = sum_e Wk[e][d]*bq[e]
__global__ __launch_bounds__(256)
void prep_t2_kernel(const __hip_bfloat16* __restrict__ WkT,
                    const float* __restrict__ bq, float* __restrict__ t2) {
  const int wave = threadIdx.x >> 6, lane = threadIdx.x & 63;
  const int d = blockIdx.x * 4 + wave;
  const short8* kr = (const short8*)(WkT + (size_t)d * DMODEL);
  float a2 = 0.f;
#pragma unroll
  for (int h = 0; h < 2; ++h) {
    const short8 kv = kr[lane * 2 + h];
    const int e0 = lane * 16 + h * 8;
#pragma unroll
    for (int i = 0; i < 8; ++i) a2 += bf2f(kv[i]) * bq[e0 + i];
  }
  a2 += __shfl_down(a2, 32); a2 += __shfl_down(a2, 16); a2 += __shfl_down(a2, 8);
  a2 += __shfl_down(a2, 4);  a2 += __shfl_down(a2, 2);  a2 += __shfl_down(a2, 1);
  if (lane == 0) t2[d] = a2;
}

// fused: x -> x8i (round(32x)) + vb'
__global__ __launch_bounds__(256)
void cvtv_kernel(const float* __restrict__ x, const float* __restrict__ t2,
                 const int* __restrict__ mask,
                 uint8_t* __restrict__ x8, float* __restrict__ vb) {
  const int wave = threadIdx.x >> 6, lane = threadIdx.x & 63;
  const size_t row = (size_t)blockIdx.x * 4 + wave;
  const float* xr = x + row * DMODEL;
  float a2 = 0.f;
#pragma unroll
  for (int p = 0; p < 4; ++p) {
    const int d = p * 256 + lane * 4;
    const float4 xv = *(const float4*)(xr + d);
    const float4 tv = *(const float4*)(t2 + d);
    a2 += xv.x * tv.x + xv.y * tv.y + xv.z * tv.z + xv.w * tv.w;
    uint32_t qp = (uint32_t)(qs8(xv.x, 32.f) & 0xff) |
                  ((uint32_t)(qs8(xv.y, 32.f) & 0xff) << 8) |
                  ((uint32_t)(qs8(xv.z, 32.f) & 0xff) << 16) |
                  ((uint32_t)(qs8(xv.w, 32.f) & 0xff) << 24);
    *(uint32_t*)(x8 + row * DMODEL + d) = qp;
  }
  a2 += __shfl_down(a2, 32); a2 += __shfl_down(a2, 16); a2 += __shfl_down(a2, 8);
  a2 += __shfl_down(a2, 4);  a2 += __shfl_down(a2, 2);  a2 += __shfl_down(a2, 1);
  if (lane == 0)
    vb[row] = mask[row] ? fmaf(a2, CS, -NEG4LN2) : -1e30f;
}

// ---------------------------------------------------------------------------
// fused zinv + passB + sumw: each block computes full rZ into LDS, then
// w[k] = sum_q E8[k][q]*rZ[q] for its 64 k rows, + per-block sumw partial.
// grid (32, nb), 256 thr.
__global__ __launch_bounds__(256)
void wsolve_kernel(const uint8_t* __restrict__ E8,
                   const float* __restrict__ Zpart,
                   float* __restrict__ wout, float* __restrict__ sumwp,
                   int b0) {
  __shared__ float rz[SEQ];
  __shared__ float sred[4];
  const int t = threadIdx.x, lane = t & 63, wave = t >> 6;
  const int cb = blockIdx.y;
  for (int q = t; q < SEQ; q += 256) {
    float z = 0.f;
#pragma unroll
    for (int kt = 0; kt < 8; ++kt)
      z += Zpart[((size_t)cb * 8 + kt) * SEQ + q];
    rz[q] = (z > 0.f) ? (1.f / z) : 0.f;
  }
  __syncthreads();
  float4 rzv[4][2];
#pragma unroll
  for (int it = 0; it < 4; ++it) {
    rzv[it][0] = *(const float4*)&rz[it * 512 + lane * 8];
    rzv[it][1] = *(const float4*)&rz[it * 512 + lane * 8 + 4];
  }
  const int kbase = blockIdx.x * 64 + wave * 16;
  float wsum = 0.f;
#pragma unroll 1
  for (int r = 0; r < 16; ++r) {
    const int k = kbase + r;
    const uint2* Ep = (const uint2*)(E8 + ((size_t)cb * SEQ + k) * SEQ);
    float s = 0.f;
#pragma unroll
    for (int it = 0; it < 4; ++it) {
      const uint2 v = Ep[it * 64 + lane];
      const float* rzp = (const float*)&rzv[it][0];
      s += __builtin_amdgcn_cvt_f32_fp8(v.x, 0) * rzp[0];
      s += __builtin_amdgcn_cvt_f32_fp8(v.x, 1) * rzp[1];
      s += __builtin_amdgcn_cvt_f32_fp8(v.x, 2) * rzp[2];
      s += __builtin_amdgcn_cvt_f32_fp8(v.x, 3) * rzp[3];
      s += __builtin_amdgcn_cvt_f32_fp8(v.y, 0) * rzp[4];
      s += __builtin_amdgcn_cvt_f32_fp8(v.y, 1) * rzp[5];
      s += __builtin_amdgcn_cvt_f32_fp8(v.y, 2) * rzp[6];
      s += __builtin_amdgcn_cvt_f32_fp8(v.y, 3) * rzp[7];
    }
    s += __shfl_down(s, 32); s += __shfl_down(s, 16); s += __shfl_down(s, 8);
    s += __shfl_down(s, 4);  s += __shfl_down(s, 2);  s += __shfl_down(s, 1);
    if (lane == 0) { wout[(size_t)cb * SEQ + k] = s; wsum += s; }
  }
  if (lane == 0) sred[wave] = wsum;
  __syncthreads();
  if (t == 0)
    sumwp[(b0 + cb) * 32 + blockIdx.x] =
        sred[0] + sred[1] + sred[2] + sred[3];
}

// wxp[kq][b][d] = (1/32) * sum_{k in chunk kq} w[k] * x8[b][k][d]
__global__ __launch_bounds__(256)
void wxpart_kernel(const uint8_t* __restrict__ x8,
                   const float* __restrict__ w,
                   float* __restrict__ wxp, int b0) {
  const int cb = blockIdx.y, kq = blockIdx.z;
  const int b = b0 + cb;
  const int d4 = threadIdx.x;
  const uint8_t* xb =
      x8 + ((size_t)b * SEQ + (size_t)kq * (SEQ / KSPLIT)) * DMODEL;
  const float* wb = w + (size_t)cb * SEQ + (size_t)kq * (SEQ / KSPLIT);
  float a0 = 0.f, a1 = 0.f, a2 = 0.f, a3 = 0.f;
#pragma unroll 4
  for (int k = 0; k < SEQ / KSPLIT; ++k) {
    const float wk = wb[k];
    const uint32_t pv = *(const uint32_t*)(xb + (size_t)k * DMODEL + d4 * 4);
    a0 += wk * (float)(int8_t)(pv & 0xff);
    a1 += wk * (float)(int8_t)((pv >> 8) & 0xff);
    a2 += wk * (float)(int8_t)((pv >> 16) & 0xff);
    a3 += wk * (float)(int8_t)(pv >> 24);
  }
  float4* o = (float4*)&wxp[((size_t)kq * NBATCH + b) * DMODEL + d4 * 4];
  *o = make_float4(a0 * 0.03125f, a1 * 0.03125f, a2 * 0.03125f, a3 * 0.03125f);
}

// out[b][e] = ( sum_d (sum_kq wxp) * Wv[e][d] + sumw[b]*bv[e] ) / SEQ
__global__ void final_kernel(const float* __restrict__ wxp,
                             const float* __restrict__ sumwp,
                             const float* __restrict__ Wv,
                             const float* __restrict__ bv,
                             float* __restrict__ out) {
  const int b = blockIdx.y, eg = blockIdx.x;
  const int wave = threadIdx.x >> 6, lane = threadIdx.x & 63;
  const int e = eg * 4 + wave;
  float acc = 0.f;
  for (int d = lane; d < DMODEL; d += 64) {
    float wx = 0.f;
#pragma unroll
    for (int kq = 0; kq < KSPLIT; ++kq)
      wx += wxp[((size_t)kq * NBATCH + b) * DMODEL + d];
    acc += wx * Wv[(size_t)e * DMODEL + d];
  }
  acc += __shfl_down(acc, 32); acc += __shfl_down(acc, 16);
  acc += __shfl_down(acc, 8);  acc += __shfl_down(acc, 4);
  acc += __shfl_down(acc, 2);  acc += __shfl_down(acc, 1);
  if (lane == 0) {
    float sw = 0.f;
#pragma unroll
    for (int i = 0; i < 32; ++i) sw += sumwp[b * 32 + i];
    out[(size_t)b * DMODEL + e] = (acc + sw * bv[e]) * (1.f / (float)SEQ);
  }
}

// ---------------------------------------------------------------------------
extern "C" void kernel_launch(void* const* d_in, const int* in_sizes, int n_in,
                              void* d_out, int out_size, void* d_ws, size_t ws_size,
                              hipStream_t stream) {
  const float* x  = (const float*)d_in[0];
  const int* mask = (const int*)d_in[1];
  const float* Wq = (const float*)d_in[2];
  const float* bq = (const float*)d_in[3];
  const float* Wk = (const float*)d_in[4];
  const float* bk = (const float*)d_in[5];
  const float* Wv = (const float*)d_in[6];
  const float* bv = (const float*)d_in[7];
  float* out = (float*)d_out;
  (void)bk;

  char* ws = (char*)d_ws;
  size_t off = 0;
  auto alloc = [&](size_t bytes) -> void* {
    void* p = ws + off;
    off += (bytes + 255) & ~(size_t)255;
    return p;
  };
  // ---- persistent ----
  uint8_t* Mt8 = (uint8_t*)alloc((size_t)DMODEL * DMODEL);
  __hip_bfloat16* WqT_bf = (__hip_bfloat16*)alloc((size_t)DMODEL * DMODEL * 2);
  __hip_bfloat16* WkT_bf = (__hip_bfloat16*)alloc((size_t)DMODEL * DMODEL * 2);
  float* wxp   = (float*)alloc((size_t)KSPLIT * NBATCH * DMODEL * 4);
  float* sumwp = (float*)alloc((size_t)NBATCH * 32 * 4);
  float* t2    = (float*)alloc((size_t)DMODEL * 4);
  uint8_t* x8i = (uint8_t*)alloc((size_t)NBATCH * SEQ * DMODEL);
  uint8_t* Y8i = (uint8_t*)alloc((size_t)NBATCH * SEQ * DMODEL);
  float* vb = (float*)alloc((size_t)NBATCH * SEQ * 4);
  const size_t fixed = off;

  // ---- per-chunk ----
  const size_t per_batch = (size_t)SEQ * SEQ      // E (fp8)
                         + (size_t)8 * SEQ * 4    // Zpart
                         + (size_t)SEQ * 4 + 8 * 256;
  long avail = (long)ws_size - (long)fixed;
  int NB = (int)(avail / (long)per_batch);
  if (NB < 1) NB = 1;
  if (NB > NBATCH) NB = NBATCH;
  while (NBATCH % NB) --NB;
  uint8_t* Ebuf = (uint8_t*)alloc((size_t)NB * SEQ * SEQ);
  float* Zpart = (float*)alloc((size_t)NB * 8 * SEQ * 4);
  float* wbuf  = (float*)alloc((size_t)NB * SEQ * 4);

  // ---- prep ----
  transpose_cvt_kernel<<<dim3(32, 32, 2), dim3(256), 0, stream>>>(
      Wq, Wk, WqT_bf, WkT_bf);
  // Mt8[d'][d] = round(1024 * sum_e WkT[d'][e]*WqT[d][e])
  gemmT_kernel<1><<<dim3(4, 4), dim3(512), 0, stream>>>(
      WqT_bf, WkT_bf, Mt8, DMODEL);
  prep_t2_kernel<<<dim3(256), dim3(256), 0, stream>>>(WkT_bf, bq, t2);
  cvtv_kernel<<<dim3(NBATCH * SEQ / 4), dim3(256), 0, stream>>>(
      x, t2, mask, x8i, vb);
  // Y8i = round( (x8 . Mt8) / 1024 ); 128 A-tiles, TP=2 -> 64 x 4 = 256 blocks
  i8gemm_kernel<0, 2><<<dim3(64, DMODEL / 256), dim3(1024), 0, stream>>>(
      x8i, Mt8, Y8i, nullptr, nullptr, 0);

  for (int b0 = 0; b0 < NBATCH; b0 += NB) {
    const int nb = NB;
    // passA: bx = cb*2+ktg (fast, XCD-pinning), by = qt
    i8gemm_kernel<1, 4><<<dim3(2 * nb, 8), dim3(1024), 0, stream>>>(
        x8i, Y8i, Ebuf, vb, Zpart, b0);
    wsolve_kernel<<<dim3(32, nb), dim3(256), 0, stream>>>(
        Ebuf, Zpart, wbuf, sumwp, b0);
    wxpart_kernel<<<dim3(1, nb, KSPLIT), dim3(256), 0, stream>>>(
        x8i, wbuf, wxp, b0);
  }
  final_kernel<<<dim3(DMODEL / 4, NBATCH), dim3(256), 0, stream>>>(
      wxp, sumwp, Wv, bv, out);
}

// Round 17
// 271.534 us; speedup vs baseline: 1.0661x; 1.0310x over previous
//
#include <hip/hip_runtime.h>
#include <hip/hip_bf16.h>
#include <stdint.h>

#define NBATCH 16
#define SEQ    2048
#define DMODEL 1024
#define KSPLIT 16

// exp((s+v)/32) * 2^-4 ; s from i8 GEMM as s_int = 1024*s_raw
#define CS      0.03125f
#define KSC     3.0517578125e-5f   // CS/1024
#define NEG4LN2 2.772588722f
#define MASKED_SENTINEL (-1e29f)

typedef __attribute__((ext_vector_type(8))) short short8;
typedef __attribute__((ext_vector_type(4))) float f32x4;
typedef __attribute__((ext_vector_type(4))) int i32x4;
typedef __attribute__((ext_vector_type(16))) int i32x16;

struct __align__(8) bf4 { __hip_bfloat16 h[4]; };

__device__ __forceinline__ float bf2f(short s) {
  union { uint32_t u; float f; } c;
  c.u = ((uint32_t)(uint16_t)s) << 16;
  return c.f;
}
__device__ __forceinline__ int qs8(float f, float sc) {
  int v = __float2int_rn(f * sc);
  return v > 127 ? 127 : (v < -127 ? -127 : v);
}

// async global -> LDS, 16B/lane. LDS dest = wave-uniform base + lane*16.
__device__ __forceinline__ void gload16(const void* g, void* l) {
  __builtin_amdgcn_global_load_lds(
      (const __attribute__((address_space(1))) void*)g,
      (__attribute__((address_space(3))) void*)l, 16, 0, 0);
}

#define BAR() __builtin_amdgcn_s_barrier()
#define WAIT_LGKM0()                                         \
  do {                                                       \
    asm volatile("s_waitcnt lgkmcnt(0)" ::: "memory");       \
    __builtin_amdgcn_sched_barrier(0);                       \
  } while (0)
#define WAIT_VM0()                                           \
  do {                                                       \
    asm volatile("s_waitcnt vmcnt(0)" ::: "memory");         \
  } while (0)

// ---------------------------------------------------------------------------
// bf16 256x256 8-wave GEMM (round-9 structure). Only used for Mt8:
// OUT int8[Brow][Arow] = clamp(round(1024 * sum_e A[Arow][e]*B[Brow][e])).
template <int TP>
__global__ __launch_bounds__(512, 2)
void gemmT_kernel(const __hip_bfloat16* __restrict__ Aall,
                  const __hip_bfloat16* __restrict__ Ball,
                  uint8_t* __restrict__ O8, int ldo) {
  __shared__ __align__(16) char smem[131072];
  const int t = threadIdx.x, lane = t & 63, wid = t >> 6;
  const int wm = wid >> 2, wn = wid & 3;
  const int g = lane >> 4, l15 = lane & 15, l7 = lane & 7;

  const int at2base = blockIdx.x * TP;
  const int bt2 = blockIdx.y;
  const __hip_bfloat16* Bb = Ball + (size_t)bt2 * 256 * DMODEL;
  auto Aof = [&](int tp) { return Aall + (size_t)(at2base + tp) * 256 * DMODEL; };

  const int srl = t >> 3;
  const int sc8 = (t & 7) ^ (srl & 7);
  const int pc8[2] = {g ^ l7, (4 + g) ^ l7};

  auto stage_mat = [&](const __hip_bfloat16* gs, char* dst, int kt) {
#pragma unroll
    for (int it = 0; it < 4; ++it)
      gload16(gs + (size_t)(it * 64 + srl) * DMODEL + kt * 64 + sc8 * 8,
              dst + it * 8192 + wid * 1024);
  };

  f32x4 acc[8][4];
#pragma unroll
  for (int m = 0; m < 8; ++m)
#pragma unroll
    for (int n = 0; n < 4; ++n) acc[m][n] = (f32x4){0.f, 0.f, 0.f, 0.f};
  short8 afr[2][4], bfr[2][2][2];

#define LDA_Q(MH)                                                           \
  { _Pragma("unroll") for (int m = 0; m < 4; ++m) {                         \
      const int row = wm * 128 + ((MH) * 4 + m) * 16 + l15;                 \
      afr[0][m] = *(const short8*)(At + row * 128 + pc8[0] * 16);           \
      afr[1][m] = *(const short8*)(At + row * 128 + pc8[1] * 16);           \
    } }
#define LDB_Q(NH)                                                           \
  { _Pragma("unroll") for (int n = 0; n < 2; ++n) {                         \
      const int row = wn * 64 + ((NH) * 2 + n) * 16 + l15;                  \
      bfr[NH][0][n] = *(const short8*)(Bt + row * 128 + pc8[0] * 16);       \
      bfr[NH][1][n] = *(const short8*)(Bt + row * 128 + pc8[1] * 16);       \
    } }
#define MFMA_Q(MH, NH)                                                      \
  { __builtin_amdgcn_s_setprio(1);                                          \
    _Pragma("unroll") for (int kk = 0; kk < 2; ++kk)                        \
    _Pragma("unroll") for (int m = 0; m < 4; ++m)                           \
    _Pragma("unroll") for (int n = 0; n < 2; ++n)                           \
      acc[(MH)*4+m][(NH)*2+n] = __builtin_amdgcn_mfma_f32_16x16x32_bf16(    \
          afr[kk][m], bfr[NH][kk][n], acc[(MH)*4+m][(NH)*2+n], 0, 0, 0);    \
    __builtin_amdgcn_s_setprio(0); }

  auto EPI = [&](int at2) {
    const size_t orow0 = (size_t)bt2 * 256 + wn * 64 + l15;
    const int ocol0 = at2 * 256 + wm * 128 + g * 4;
#pragma unroll
    for (int mi = 0; mi < 8; ++mi)
#pragma unroll
      for (int ni = 0; ni < 4; ++ni) {
        uint32_t pk = 0;
#pragma unroll
        for (int j = 0; j < 4; ++j)
          pk |= (uint32_t)(qs8(acc[mi][ni][j], 1024.f) & 0xff) << (8 * j);
        *(uint32_t*)(O8 + (orow0 + ni * 16) * (size_t)ldo + ocol0 + mi * 16) = pk;
      }
#pragma unroll
    for (int m = 0; m < 8; ++m)
#pragma unroll
      for (int n = 0; n < 4; ++n) acc[m][n] = (f32x4){0.f, 0.f, 0.f, 0.f};
  };

  stage_mat(Aof(0), smem, 0);
  stage_mat(Bb, smem + 32768, 0);
  WAIT_VM0();
  BAR();

  const int NI = 16 * TP;
#pragma unroll 1
  for (int ii = 0; ii < NI; ++ii) {
    const int p = ii & 1;
    const char* At = smem + (p << 16);
    const char* Bt = smem + 32768 + (p << 16);
    char* An = smem + ((p ^ 1) << 16);
    char* Bn = smem + 32768 + ((p ^ 1) << 16);
    const int kn = (ii + 1) & 15;
    LDA_Q(0) LDB_Q(0)
    if (ii + 1 < NI) stage_mat(Aof((ii + 1) >> 4), An, kn);
    BAR(); WAIT_LGKM0(); MFMA_Q(0, 0) BAR();
    LDB_Q(1)
    if (ii + 1 < NI) stage_mat(Bb, Bn, kn);
    BAR(); WAIT_LGKM0(); MFMA_Q(0, 1) BAR();
    LDA_Q(1)
    BAR(); WAIT_LGKM0(); MFMA_Q(1, 0) BAR();
    MFMA_Q(1, 1)
    WAIT_VM0();
    if ((ii & 15) == 15) EPI(at2base + (ii >> 4));
    BAR();
  }
#undef LDA_Q
#undef LDB_Q
#undef MFMA_Q
}

// ---------------------------------------------------------------------------
// int8 256x256 tile over 16 waves (1024 thr), K-step 128B, dbuf 128KiB LDS,
// mfma_i32_32x32x32_i8 (round-14 schedule).
// MODE 0: Y8[arow][bcol] = clamp(round(acc/1024)). grid (128/TP, 4).
// MODE 1: passA. grid 3D (nb, 2 ktg, 8 qt): flat%8 = cb%8 -> both ktg of a
//         batch AND all its A-panel-sharing qt blocks pin to ONE XCD (B and
//         A panels both L2-shared). Masked k rows (vb' sentinel): exp+store
//         skipped entirely (E rows never touched).
template <int MODE, int TP>
__global__ __launch_bounds__(1024)
void i8gemm_kernel(const uint8_t* __restrict__ Aall,
                   const uint8_t* __restrict__ Ball,
                   uint8_t* __restrict__ OUT8,
                   const float* __restrict__ vball,
                   float* __restrict__ Zpart, int b0) {
  __shared__ __align__(16) char smem[131072 + 4096];
  const int t = threadIdx.x, lane = t & 63, wid = t >> 6;  // 16 waves
  const int wm = wid >> 2, wn = wid & 3;                   // 4x4 of 64x64
  const int l31 = lane & 31, half = lane >> 5, l7 = lane & 7;

  int at2base, bt2, cb = 0, b = 0;
  const uint8_t *Bb, *Abatch;
  if constexpr (MODE == 0) {
    at2base = blockIdx.x * TP;
    bt2 = blockIdx.y;
    Abatch = Aall;
    Bb = Ball + (size_t)bt2 * 256 * DMODEL;
  } else {
    cb = blockIdx.x; b = b0 + cb;        // batch, FAST dim -> XCD = cb%8
    at2base = blockIdx.y * TP;           // ktg
    bt2 = blockIdx.z;                    // q-tile (256 q)
    Abatch = Aall + (size_t)b * SEQ * DMODEL;
    Bb = Ball + ((size_t)b * SEQ + bt2 * 256) * DMODEL;
  }
  auto Aof = [&](int tp) { return Abatch + (size_t)(at2base + tp) * 256 * DMODEL; };

  const int sc8 = (t & 7) ^ ((t >> 3) & 7);   // pre-swizzled source 16B-slot
  int pcI[4];
#pragma unroll
  for (int ks = 0; ks < 4; ++ks) pcI[ks] = ((ks * 2 + half) ^ l7) * 16;

  // 32KB tile: [256 rows][8 slots of 16B], slot XOR row&7. 1024thr x 2 loads.
  auto stage_mat = [&](const uint8_t* gs, char* dst, int kt) {
#pragma unroll
    for (int it = 0; it < 2; ++it)
      gload16(gs + (size_t)(it * 128 + (t >> 3)) * DMODEL + kt * 128 + sc8 * 16,
              dst + it * 16384 + wid * 1024);
  };

  i32x16 acci[2][2];
#pragma unroll
  for (int m = 0; m < 2; ++m)
#pragma unroll
    for (int n = 0; n < 2; ++n)
#pragma unroll
      for (int r = 0; r < 16; ++r) acci[m][n][r] = 0;

  auto EPI = [&](int at2) {
    if constexpr (MODE == 0) {
#pragma unroll
      for (int mt = 0; mt < 2; ++mt) {
        const int arow_base = at2 * 256 + wm * 64 + mt * 32 + 4 * half;
#pragma unroll
        for (int nt = 0; nt < 2; ++nt) {
          const int bcol = bt2 * 256 + wn * 64 + nt * 32 + l31;
#pragma unroll
          for (int r = 0; r < 16; ++r) {
            const int arow = arow_base + (r & 3) + 8 * (r >> 2);
            OUT8[(size_t)arow * DMODEL + bcol] =
                (uint8_t)qs8((float)acci[mt][nt][r], 9.765625e-4f);  // /1024
          }
        }
      }
    } else {
      float zc[2] = {0.f, 0.f};
#pragma unroll
      for (int mt = 0; mt < 2; ++mt) {
        const int krow_base = at2 * 256 + wm * 64 + mt * 32 + 4 * half;
        float4 vv[4];
#pragma unroll
        for (int gg = 0; gg < 4; ++gg)
          vv[gg] = *(const float4*)&vball[(size_t)b * SEQ + krow_base + 8 * gg];
#pragma unroll
        for (int nt = 0; nt < 2; ++nt) {
          const int qcol = bt2 * 256 + wn * 64 + nt * 32 + l31;
#pragma unroll
          for (int r = 0; r < 16; r += 2) {
            const float vj0 = ((const float*)&vv[r >> 2])[r & 3];
            const float vj1 = ((const float*)&vv[r >> 2])[(r + 1) & 3];
            const bool m0 = vj0 > MASKED_SENTINEL;
            const bool m1 = vj1 > MASKED_SENTINEL;
            const float e0 =
                m0 ? __expf(fmaf((float)acci[mt][nt][r], KSC, vj0)) : 0.f;
            const float e1 =
                m1 ? __expf(fmaf((float)acci[mt][nt][r + 1], KSC, vj1)) : 0.f;
            zc[nt] += e0 + e1;
            const unsigned p = __builtin_amdgcn_cvt_pk_fp8_f32(e0, e1, 0, false);
            const int krow = krow_base + (r & 3) + 8 * (r >> 2);
            uint8_t* ad = OUT8 + ((size_t)cb * SEQ + krow) * (size_t)SEQ + qcol;
            if (m0) ad[0] = (uint8_t)p;            // masked rows never written
            if (m1) ad[SEQ] = (uint8_t)(p >> 8);
          }
        }
      }
#pragma unroll
      for (int nt = 0; nt < 2; ++nt) {
        float v = zc[nt];
        v += __shfl_xor(v, 32);
        zc[nt] = v;
      }
      float* red = (float*)(smem + 131072);   // [4 wm][256 q]
      if (lane < 32) {
#pragma unroll
        for (int nt = 0; nt < 2; ++nt)
          red[wm * 256 + wn * 64 + nt * 32 + l31] = zc[nt];
      }
      __syncthreads();
      if (t < 256)
        Zpart[((size_t)cb * 8 + at2) * SEQ + bt2 * 256 + t] =
            red[t] + red[256 + t] + red[512 + t] + red[768 + t];
    }
#pragma unroll
    for (int m = 0; m < 2; ++m)
#pragma unroll
      for (int n = 0; n < 2; ++n)
#pragma unroll
        for (int r = 0; r < 16; ++r) acci[m][n][r] = 0;
  };

  // prologue: tile 0 -> buf0
  stage_mat(Aof(0), smem, 0);
  stage_mat(Bb, smem + 32768, 0);
  WAIT_VM0();
  BAR();

  const int NI = 8 * TP;   // 8 K-steps of 128B per k-tile
#pragma unroll 1
  for (int ii = 0; ii < NI; ++ii) {
    const int p = ii & 1;
    const char* Al = smem + (p << 16);
    const char* Bl = smem + 32768 + (p << 16);
    // issue next-tile stage FIRST (max issue->drain distance)
    if (ii + 1 < NI) {
      stage_mat(Aof((ii + 1) >> 3), smem + ((p ^ 1) << 16), (ii + 1) & 7);
      stage_mat(Bb, smem + 32768 + ((p ^ 1) << 16), (ii + 1) & 7);
    }
    const int rA0 = (wm * 64 + l31) * 128, rA1 = (wm * 64 + 32 + l31) * 128;
    const int rB0 = (wn * 64 + l31) * 128, rB1 = (wn * 64 + 32 + l31) * 128;
#pragma unroll
    for (int ks = 0; ks < 4; ++ks) {
      const i32x4 af0 = *(const i32x4*)(Al + rA0 + pcI[ks]);
      const i32x4 af1 = *(const i32x4*)(Al + rA1 + pcI[ks]);
      const i32x4 bf0 = *(const i32x4*)(Bl + rB0 + pcI[ks]);
      const i32x4 bf1 = *(const i32x4*)(Bl + rB1 + pcI[ks]);
      __builtin_amdgcn_s_setprio(1);
      acci[0][0] = __builtin_amdgcn_mfma_i32_32x32x32_i8(af0, bf0, acci[0][0], 0, 0, 0);
      acci[0][1] = __builtin_amdgcn_mfma_i32_32x32x32_i8(af0, bf1, acci[0][1], 0, 0, 0);
      acci[1][0] = __builtin_amdgcn_mfma_i32_32x32x32_i8(af1, bf0, acci[1][0], 0, 0, 0);
      acci[1][1] = __builtin_amdgcn_mfma_i32_32x32x32_i8(af1, bf1, acci[1][1], 0, 0, 0);
      __builtin_amdgcn_s_setprio(0);
    }
    WAIT_LGKM0();   // all my ds-reads of buf p drained before crossing barrier
    WAIT_VM0();     // next tile landed
    if ((ii & 7) == 7) EPI(at2base + (ii >> 3));
    BAR();
  }
}

// ---------------------------------------------------------------------------
// fp32 [DMODEL][DMODEL] -> bf16 transposed; z selects (Wq->WqT, Wk->WkT)
__global__ void transpose_cvt_kernel(const float* __restrict__ inq,
                                     const float* __restrict__ ink,
                                     __hip_bfloat16* __restrict__ outq,
                                     __hip_bfloat16* __restrict__ outk) {
  __shared__ float tile[32][33];
  const float* in = blockIdx.z ? ink : inq;
  __hip_bfloat16* outp = blockIdx.z ? outk : outq;
  const int bx = blockIdx.x, by = blockIdx.y;
  const int tx = threadIdx.x & 31, ty = threadIdx.x >> 5;
#pragma unroll
  for (int r = 0; r < 32; r += 8)
    tile[ty + r][tx] = in[(size_t)(by * 32 + ty + r) * DMODEL + bx * 32 + tx];
  __syncthreads();
#pragma unroll
  for (int r = 0; r < 32; r += 8)
    outp[(size_t)(bx * 32 + ty + r) * DMODEL + by * 32 + tx] =
        __float2bfloat16(tile[tx][ty + r]);
}

// t2[d] = sum_e Wk[e][d]*bq[e]
__global__ __launch_bounds__(256)
void prep_t2_kernel(const __hip_bfloat16* __restrict__ WkT,
                    const float* __restrict__ bq, float* __restrict__ t2) {
  const int wave = threadIdx.x >> 6, lane = threadIdx.x & 63;
  const int d = blockIdx.x * 4 + wave;
  const short8* kr = (const short8*)(WkT + (size_t)d * DMODEL);
  float a2 = 0.f;
#pragma unroll
  for (int h = 0; h < 2; ++h) {
    const short8 kv = kr[lane * 2 + h];
    const int e0 = lane * 16 + h * 8;
#pragma unroll
    for (int i = 0; i < 8; ++i) a2 += bf2f(kv[i]) * bq[e0 + i];
  }
  a2 += __shfl_down(a2, 32); a2 += __shfl_down(a2, 16); a2 += __shfl_down(a2, 8);
  a2 += __shfl_down(a2, 4);  a2 += __shfl_down(a2, 2);  a2 += __shfl_down(a2, 1);
  if (lane == 0) t2[d] = a2;
}

// fused: x -> x8i (round(32x)) + vb'
__global__ __launch_bounds__(256)
void cvtv_kernel(const float* __restrict__ x, const float* __restrict__ t2,
                 const int* __restrict__ mask,
                 uint8_t* __restrict__ x8, float* __restrict__ vb) {
  const int wave = threadIdx.x >> 6, lane = threadIdx.x & 63;
  const size_t row = (size_t)blockIdx.x * 4 + wave;
  const float* xr = x + row * DMODEL;
  float a2 = 0.f;
#pragma unroll
  for (int p = 0; p < 4; ++p) {
    const int d = p * 256 + lane * 4;
    const float4 xv = *(const float4*)(xr + d);
    const float4 tv = *(const float4*)(t2 + d);
    a2 += xv.x * tv.x + xv.y * tv.y + xv.z * tv.z + xv.w * tv.w;
    uint32_t qp = (uint32_t)(qs8(xv.x, 32.f) & 0xff) |
                  ((uint32_t)(qs8(xv.y, 32.f) & 0xff) << 8) |
                  ((uint32_t)(qs8(xv.z, 32.f) & 0xff) << 16) |
                  ((uint32_t)(qs8(xv.w, 32.f) & 0xff) << 24);
    *(uint32_t*)(x8 + row * DMODEL + d) = qp;
  }
  a2 += __shfl_down(a2, 32); a2 += __shfl_down(a2, 16); a2 += __shfl_down(a2, 8);
  a2 += __shfl_down(a2, 4);  a2 += __shfl_down(a2, 2);  a2 += __shfl_down(a2, 1);
  if (lane == 0)
    vb[row] = mask[row] ? fmaf(a2, CS, -NEG4LN2) : -1e30f;
}

// ---------------------------------------------------------------------------
// fused zinv + passB + sumw: each block computes full rZ into LDS, then
// w[k] = sum_q E8[k][q]*rZ[q] for its 64 k rows (masked rows skipped: w=0,
// E never read), + per-block sumw partial. grid (32, nb), 256 thr.
__global__ __launch_bounds__(256)
void wsolve_kernel(const uint8_t* __restrict__ E8,
                   const float* __restrict__ Zpart,
                   const int* __restrict__ mask,
                   float* __restrict__ wout, float* __restrict__ sumwp,
                   int b0) {
  __shared__ float rz[SEQ];
  __shared__ float sred[4];
  const int t = threadIdx.x, lane = t & 63, wave = t >> 6;
  const int cb = blockIdx.y;
  for (int q = t; q < SEQ; q += 256) {
    float z = 0.f;
#pragma unroll
    for (int kt = 0; kt < 8; ++kt)
      z += Zpart[((size_t)cb * 8 + kt) * SEQ + q];
    rz[q] = (z > 0.f) ? (1.f / z) : 0.f;
  }
  __syncthreads();
  float4 rzv[4][2];
#pragma unroll
  for (int it = 0; it < 4; ++it) {
    rzv[it][0] = *(const float4*)&rz[it * 512 + lane * 8];
    rzv[it][1] = *(const float4*)&rz[it * 512 + lane * 8 + 4];
  }
  const int kbase = blockIdx.x * 64 + wave * 16;
  float wsum = 0.f;
#pragma unroll 1
  for (int r = 0; r < 16; ++r) {
    const int k = kbase + r;
    if (!mask[(size_t)(b0 + cb) * SEQ + k]) {
      if (lane == 0) wout[(size_t)cb * SEQ + k] = 0.f;
      continue;
    }
    const uint2* Ep = (const uint2*)(E8 + ((size_t)cb * SEQ + k) * SEQ);
    float s = 0.f;
#pragma unroll
    for (int it = 0; it < 4; ++it) {
      const uint2 v = Ep[it * 64 + lane];
      const float* rzp = (const float*)&rzv[it][0];
      s += __builtin_amdgcn_cvt_f32_fp8(v.x, 0) * rzp[0];
      s += __builtin_amdgcn_cvt_f32_fp8(v.x, 1) * rzp[1];
      s += __builtin_amdgcn_cvt_f32_fp8(v.x, 2) * rzp[2];
      s += __builtin_amdgcn_cvt_f32_fp8(v.x, 3) * rzp[3];
      s += __builtin_amdgcn_cvt_f32_fp8(v.y, 0) * rzp[4];
      s += __builtin_amdgcn_cvt_f32_fp8(v.y, 1) * rzp[5];
      s += __builtin_amdgcn_cvt_f32_fp8(v.y, 2) * rzp[6];
      s += __builtin_amdgcn_cvt_f32_fp8(v.y, 3) * rzp[7];
    }
    s += __shfl_down(s, 32); s += __shfl_down(s, 16); s += __shfl_down(s, 8);
    s += __shfl_down(s, 4);  s += __shfl_down(s, 2);  s += __shfl_down(s, 1);
    if (lane == 0) { wout[(size_t)cb * SEQ + k] = s; wsum += s; }
  }
  if (lane == 0) sred[wave] = wsum;
  __syncthreads();
  if (t == 0)
    sumwp[(b0 + cb) * 32 + blockIdx.x] =
        sred[0] + sred[1] + sred[2] + sred[3];
}

// wxp[kq][b][d] = (1/32) * sum_{k in chunk kq} w[k] * x8[b][k][d]
__global__ __launch_bounds__(256)
void wxpart_kernel(const uint8_t* __restrict__ x8,
                   const float* __restrict__ w,
                   float* __restrict__ wxp, int b0) {
  const int cb = blockIdx.y, kq = blockIdx.z;
  const int b = b0 + cb;
  const int d4 = threadIdx.x;
  const uint8_t* xb =
      x8 + ((size_t)b * SEQ + (size_t)kq * (SEQ / KSPLIT)) * DMODEL;
  const float* wb = w + (size_t)cb * SEQ + (size_t)kq * (SEQ / KSPLIT);
  float a0 = 0.f, a1 = 0.f, a2 = 0.f, a3 = 0.f;
#pragma unroll 4
  for (int k = 0; k < SEQ / KSPLIT; ++k) {
    const float wk = wb[k];
    const uint32_t pv = *(const uint32_t*)(xb + (size_t)k * DMODEL + d4 * 4);
    a0 += wk * (float)(int8_t)(pv & 0xff);
    a1 += wk * (float)(int8_t)((pv >> 8) & 0xff);
    a2 += wk * (float)(int8_t)((pv >> 16) & 0xff);
    a3 += wk * (float)(int8_t)(pv >> 24);
  }
  float4* o = (float4*)&wxp[((size_t)kq * NBATCH + b) * DMODEL + d4 * 4];
  *o = make_float4(a0 * 0.03125f, a1 * 0.03125f, a2 * 0.03125f, a3 * 0.03125f);
}

// out[b][e] = ( sum_d (sum_kq wxp) * Wv[e][d] + sumw[b]*bv[e] ) / SEQ
__global__ void final_kernel(const float* __restrict__ wxp,
                             const float* __restrict__ sumwp,
                             const float* __restrict__ Wv,
                             const float* __restrict__ bv,
                             float* __restrict__ out) {
  const int b = blockIdx.y, eg = blockIdx.x;
  const int wave = threadIdx.x >> 6, lane = threadIdx.x & 63;
  const int e = eg * 4 + wave;
  float acc = 0.f;
  for (int d = lane; d < DMODEL; d += 64) {
    float wx = 0.f;
#pragma unroll
    for (int kq = 0; kq < KSPLIT; ++kq)
      wx += wxp[((size_t)kq * NBATCH + b) * DMODEL + d];
    acc += wx * Wv[(size_t)e * DMODEL + d];
  }
  acc += __shfl_down(acc, 32); acc += __shfl_down(acc, 16);
  acc += __shfl_down(acc, 8);  acc += __shfl_down(acc, 4);
  acc += __shfl_down(acc, 2);  acc += __shfl_down(acc, 1);
  if (lane == 0) {
    float sw = 0.f;
#pragma unroll
    for (int i = 0; i < 32; ++i) sw += sumwp[b * 32 + i];
    out[(size_t)b * DMODEL + e] = (acc + sw * bv[e]) * (1.f / (float)SEQ);
  }
}

// ---------------------------------------------------------------------------
extern "C" void kernel_launch(void* const* d_in, const int* in_sizes, int n_in,
                              void* d_out, int out_size, void* d_ws, size_t ws_size,
                              hipStream_t stream) {
  const float* x  = (const float*)d_in[0];
  const int* mask = (const int*)d_in[1];
  const float* Wq = (const float*)d_in[2];
  const float* bq = (const float*)d_in[3];
  const float* Wk = (const float*)d_in[4];
  const float* bk = (const float*)d_in[5];
  const float* Wv = (const float*)d_in[6];
  const float* bv = (const float*)d_in[7];
  float* out = (float*)d_out;
  (void)bk;

  char* ws = (char*)d_ws;
  size_t off = 0;
  auto alloc = [&](size_t bytes) -> void* {
    void* p = ws + off;
    off += (bytes + 255) & ~(size_t)255;
    return p;
  };
  // ---- persistent ----
  uint8_t* Mt8 = (uint8_t*)alloc((size_t)DMODEL * DMODEL);
  __hip_bfloat16* WqT_bf = (__hip_bfloat16*)alloc((size_t)DMODEL * DMODEL * 2);
  __hip_bfloat16* WkT_bf = (__hip_bfloat16*)alloc((size_t)DMODEL * DMODEL * 2);
  float* wxp   = (float*)alloc((size_t)KSPLIT * NBATCH * DMODEL * 4);
  float* sumwp = (float*)alloc((size_t)NBATCH * 32 * 4);
  float* t2    = (float*)alloc((size_t)DMODEL * 4);
  uint8_t* x8i = (uint8_t*)alloc((size_t)NBATCH * SEQ * DMODEL);
  uint8_t* Y8i = (uint8_t*)alloc((size_t)NBATCH * SEQ * DMODEL);
  float* vb = (float*)alloc((size_t)NBATCH * SEQ * 4);
  const size_t fixed = off;

  // ---- per-chunk ----
  const size_t per_batch = (size_t)SEQ * SEQ      // E (fp8)
                         + (size_t)8 * SEQ * 4    // Zpart
                         + (size_t)SEQ * 4 + 8 * 256;
  long avail = (long)ws_size - (long)fixed;
  int NB = (int)(avail / (long)per_batch);
  if (NB < 1) NB = 1;
  if (NB > NBATCH) NB = NBATCH;
  while (NBATCH % NB) --NB;
  uint8_t* Ebuf = (uint8_t*)alloc((size_t)NB * SEQ * SEQ);
  float* Zpart = (float*)alloc((size_t)NB * 8 * SEQ * 4);
  float* wbuf  = (float*)alloc((size_t)NB * SEQ * 4);

  // ---- prep ----
  transpose_cvt_kernel<<<dim3(32, 32, 2), dim3(256), 0, stream>>>(
      Wq, Wk, WqT_bf, WkT_bf);
  // Mt8[d'][d] = round(1024 * sum_e WkT[d'][e]*WqT[d][e])
  gemmT_kernel<1><<<dim3(4, 4), dim3(512), 0, stream>>>(
      WqT_bf, WkT_bf, Mt8, DMODEL);
  prep_t2_kernel<<<dim3(256), dim3(256), 0, stream>>>(WkT_bf, bq, t2);
  cvtv_kernel<<<dim3(NBATCH * SEQ / 4), dim3(256), 0, stream>>>(
      x, t2, mask, x8i, vb);
  // Y8i = round( (x8 . Mt8) / 1024 ); 128 A-tiles, TP=2 -> 64 x 4 = 256 blocks
  i8gemm_kernel<0, 2><<<dim3(64, DMODEL / 256), dim3(1024), 0, stream>>>(
      x8i, Mt8, Y8i, nullptr, nullptr, 0);

  for (int b0 = 0; b0 < NBATCH; b0 += NB) {
    const int nb = NB;
    // passA: 3D grid (cb fast -> XCD pin; ktg; qt)
    i8gemm_kernel<1, 4><<<dim3(nb, 2, 8), dim3(1024), 0, stream>>>(
        x8i, Y8i, Ebuf, vb, Zpart, b0);
    wsolve_kernel<<<dim3(32, nb), dim3(256), 0, stream>>>(
        Ebuf, Zpart, mask, wbuf, sumwp, b0);
    wxpart_kernel<<<dim3(1, nb, KSPLIT), dim3(256), 0, stream>>>(
        x8i, wbuf, wxp, b0);
  }
  final_kernel<<<dim3(DMODEL / 4, NBATCH), dim3(256), 0, stream>>>(
      wxp, sumwp, Wv, bv, out);
}

// Round 19
// 271.229 us; speedup vs baseline: 1.0673x; 1.0011x over previous
//
#include <hip/hip_runtime.h>
#include <hip/hip_bf16.h>
#include <stdint.h>

#define NBATCH 16
#define SEQ    2048
#define DMODEL 1024
#define KSPLIT 16

// exp((s+v)/32) * 2^-4 ; s from i8 GEMM as s_int = 1024*s_raw
#define CS      0.03125f
#define KSC     3.0517578125e-5f   // CS/1024
#define NEG4LN2 2.772588722f
#define MASKED_SENTINEL (-1e29f)

typedef __attribute__((ext_vector_type(8))) short short8;
typedef __attribute__((ext_vector_type(4))) float f32x4;
typedef __attribute__((ext_vector_type(4))) int i32x4;
typedef __attribute__((ext_vector_type(16))) int i32x16;

struct __align__(8) bf4 { __hip_bfloat16 h[4]; };

__device__ __forceinline__ float bf2f(short s) {
  union { uint32_t u; float f; } c;
  c.u = ((uint32_t)(uint16_t)s) << 16;
  return c.f;
}
__device__ __forceinline__ int qs8(float f, float sc) {
  int v = __float2int_rn(f * sc);
  return v > 127 ? 127 : (v < -127 ? -127 : v);
}

// async global -> LDS, 16B/lane. LDS dest = wave-uniform base + lane*16.
__device__ __forceinline__ void gload16(const void* g, void* l) {
  __builtin_amdgcn_global_load_lds(
      (const __attribute__((address_space(1))) void*)g,
      (__attribute__((address_space(3))) void*)l, 16, 0, 0);
}

#define BAR() __builtin_amdgcn_s_barrier()
#define WAIT_LGKM0()                                         \
  do {                                                       \
    asm volatile("s_waitcnt lgkmcnt(0)" ::: "memory");       \
    __builtin_amdgcn_sched_barrier(0);                       \
  } while (0)
#define WAIT_VM0()                                           \
  do {                                                       \
    asm volatile("s_waitcnt vmcnt(0)" ::: "memory");         \
  } while (0)

// ---------------------------------------------------------------------------
// bf16 256x256 8-wave GEMM (round-9 structure). Only used for Mt8:
// OUT int8[Brow][Arow] = clamp(round(1024 * sum_e A[Arow][e]*B[Brow][e])).
template <int TP>
__global__ __launch_bounds__(512, 2)
void gemmT_kernel(const __hip_bfloat16* __restrict__ Aall,
                  const __hip_bfloat16* __restrict__ Ball,
                  uint8_t* __restrict__ O8, int ldo) {
  __shared__ __align__(16) char smem[131072];
  const int t = threadIdx.x, lane = t & 63, wid = t >> 6;
  const int wm = wid >> 2, wn = wid & 3;
  const int g = lane >> 4, l15 = lane & 15, l7 = lane & 7;

  const int at2base = blockIdx.x * TP;
  const int bt2 = blockIdx.y;
  const __hip_bfloat16* Bb = Ball + (size_t)bt2 * 256 * DMODEL;
  auto Aof = [&](int tp) { return Aall + (size_t)(at2base + tp) * 256 * DMODEL; };

  const int srl = t >> 3;
  const int sc8 = (t & 7) ^ (srl & 7);
  const int pc8[2] = {g ^ l7, (4 + g) ^ l7};

  auto stage_mat = [&](const __hip_bfloat16* gs, char* dst, int kt) {
#pragma unroll
    for (int it = 0; it < 4; ++it)
      gload16(gs + (size_t)(it * 64 + srl) * DMODEL + kt * 64 + sc8 * 8,
              dst + it * 8192 + wid * 1024);
  };

  f32x4 acc[8][4];
#pragma unroll
  for (int m = 0; m < 8; ++m)
#pragma unroll
    for (int n = 0; n < 4; ++n) acc[m][n] = (f32x4){0.f, 0.f, 0.f, 0.f};
  short8 afr[2][4], bfr[2][2][2];

#define LDA_Q(MH)                                                           \
  { _Pragma("unroll") for (int m = 0; m < 4; ++m) {                         \
      const int row = wm * 128 + ((MH) * 4 + m) * 16 + l15;                 \
      afr[0][m] = *(const short8*)(At + row * 128 + pc8[0] * 16);           \
      afr[1][m] = *(const short8*)(At + row * 128 + pc8[1] * 16);           \
    } }
#define LDB_Q(NH)                                                           \
  { _Pragma("unroll") for (int n = 0; n < 2; ++n) {                         \
      const int row = wn * 64 + ((NH) * 2 + n) * 16 + l15;                  \
      bfr[NH][0][n] = *(const short8*)(Bt + row * 128 + pc8[0] * 16);       \
      bfr[NH][1][n] = *(const short8*)(Bt + row * 128 + pc8[1] * 16);       \
    } }
#define MFMA_Q(MH, NH)                                                      \
  { __builtin_amdgcn_s_setprio(1);                                          \
    _Pragma("unroll") for (int kk = 0; kk < 2; ++kk)                        \
    _Pragma("unroll") for (int m = 0; m < 4; ++m)                           \
    _Pragma("unroll") for (int n = 0; n < 2; ++n)                           \
      acc[(MH)*4+m][(NH)*2+n] = __builtin_amdgcn_mfma_f32_16x16x32_bf16(    \
          afr[kk][m], bfr[NH][kk][n], acc[(MH)*4+m][(NH)*2+n], 0, 0, 0);    \
    __builtin_amdgcn_s_setprio(0); }

  auto EPI = [&](int at2) {
    const size_t orow0 = (size_t)bt2 * 256 + wn * 64 + l15;
    const int ocol0 = at2 * 256 + wm * 128 + g * 4;
#pragma unroll
    for (int mi = 0; mi < 8; ++mi)
#pragma unroll
      for (int ni = 0; ni < 4; ++ni) {
        uint32_t pk = 0;
#pragma unroll
        for (int j = 0; j < 4; ++j)
          pk |= (uint32_t)(qs8(acc[mi][ni][j], 1024.f) & 0xff) << (8 * j);
        *(uint32_t*)(O8 + (orow0 + ni * 16) * (size_t)ldo + ocol0 + mi * 16) = pk;
      }
#pragma unroll
    for (int m = 0; m < 8; ++m)
#pragma unroll
      for (int n = 0; n < 4; ++n) acc[m][n] = (f32x4){0.f, 0.f, 0.f, 0.f};
  };

  stage_mat(Aof(0), smem, 0);
  stage_mat(Bb, smem + 32768, 0);
  WAIT_VM0();
  BAR();

  const int NI = 16 * TP;
#pragma unroll 1
  for (int ii = 0; ii < NI; ++ii) {
    const int p = ii & 1;
    const char* At = smem + (p << 16);
    const char* Bt = smem + 32768 + (p << 16);
    char* An = smem + ((p ^ 1) << 16);
    char* Bn = smem + 32768 + ((p ^ 1) << 16);
    const int kn = (ii + 1) & 15;
    LDA_Q(0) LDB_Q(0)
    if (ii + 1 < NI) stage_mat(Aof((ii + 1) >> 4), An, kn);
    BAR(); WAIT_LGKM0(); MFMA_Q(0, 0) BAR();
    LDB_Q(1)
    if (ii + 1 < NI) stage_mat(Bb, Bn, kn);
    BAR(); WAIT_LGKM0(); MFMA_Q(0, 1) BAR();
    LDA_Q(1)
    BAR(); WAIT_LGKM0(); MFMA_Q(1, 0) BAR();
    MFMA_Q(1, 1)
    WAIT_VM0();
    if ((ii & 15) == 15) EPI(at2base + (ii >> 4));
    BAR();
  }
#undef LDA_Q
#undef LDB_Q
#undef MFMA_Q
}

// ---------------------------------------------------------------------------
// int8 256x256 tile over 16 waves (1024 thr), K-step 128B, dbuf 128KiB LDS,
// mfma_i32_32x32x32_i8 (round-14 schedule — the proven best).
// MODE 0: Y8[arow][bcol] = clamp(round(acc/1024)). grid (128/TP, 4).
// MODE 1: passA. grid 3D (nb, 2 ktg, 8 qt): flat%8 = cb%8 -> XCD pinning
//         (A and B panels L2-shared). Masked k rows (vb' sentinel): exp+store
//         skipped entirely (E rows never touched).
template <int MODE, int TP>
__global__ __launch_bounds__(1024)
void i8gemm_kernel(const uint8_t* __restrict__ Aall,
                   const uint8_t* __restrict__ Ball,
                   uint8_t* __restrict__ OUT8,
                   const float* __restrict__ vball,
                   float* __restrict__ Zpart, int b0) {
  __shared__ __align__(16) char smem[131072 + 4096];
  const int t = threadIdx.x, lane = t & 63, wid = t >> 6;  // 16 waves
  const int wm = wid >> 2, wn = wid & 3;                   // 4x4 of 64x64
  const int l31 = lane & 31, half = lane >> 5, l7 = lane & 7;

  int at2base, bt2, cb = 0, b = 0;
  const uint8_t *Bb, *Abatch;
  if constexpr (MODE == 0) {
    at2base = blockIdx.x * TP;
    bt2 = blockIdx.y;
    Abatch = Aall;
    Bb = Ball + (size_t)bt2 * 256 * DMODEL;
  } else {
    cb = blockIdx.x; b = b0 + cb;        // batch, FAST dim -> XCD = cb%8
    at2base = blockIdx.y * TP;           // ktg
    bt2 = blockIdx.z;                    // q-tile (256 q)
    Abatch = Aall + (size_t)b * SEQ * DMODEL;
    Bb = Ball + ((size_t)b * SEQ + bt2 * 256) * DMODEL;
  }
  auto Aof = [&](int tp) { return Abatch + (size_t)(at2base + tp) * 256 * DMODEL; };

  const int sc8 = (t & 7) ^ ((t >> 3) & 7);   // pre-swizzled source 16B-slot
  int pcI[4];
#pragma unroll
  for (int ks = 0; ks < 4; ++ks) pcI[ks] = ((ks * 2 + half) ^ l7) * 16;

  // 32KB tile: [256 rows][8 slots of 16B], slot XOR row&7. 1024thr x 2 loads.
  auto stage_mat = [&](const uint8_t* gs, char* dst, int kt) {
#pragma unroll
    for (int it = 0; it < 2; ++it)
      gload16(gs + (size_t)(it * 128 + (t >> 3)) * DMODEL + kt * 128 + sc8 * 16,
              dst + it * 16384 + wid * 1024);
  };

  i32x16 acci[2][2];
#pragma unroll
  for (int m = 0; m < 2; ++m)
#pragma unroll
    for (int n = 0; n < 2; ++n)
#pragma unroll
      for (int r = 0; r < 16; ++r) acci[m][n][r] = 0;

  auto EPI = [&](int at2) {
    if constexpr (MODE == 0) {
#pragma unroll
      for (int mt = 0; mt < 2; ++mt) {
        const int arow_base = at2 * 256 + wm * 64 + mt * 32 + 4 * half;
#pragma unroll
        for (int nt = 0; nt < 2; ++nt) {
          const int bcol = bt2 * 256 + wn * 64 + nt * 32 + l31;
#pragma unroll
          for (int r = 0; r < 16; ++r) {
            const int arow = arow_base + (r & 3) + 8 * (r >> 2);
            OUT8[(size_t)arow * DMODEL + bcol] =
                (uint8_t)qs8((float)acci[mt][nt][r], 9.765625e-4f);  // /1024
          }
        }
      }
    } else {
      float zc[2] = {0.f, 0.f};
#pragma unroll
      for (int mt = 0; mt < 2; ++mt) {
        const int krow_base = at2 * 256 + wm * 64 + mt * 32 + 4 * half;
        float4 vv[4];
#pragma unroll
        for (int gg = 0; gg < 4; ++gg)
          vv[gg] = *(const float4*)&vball[(size_t)b * SEQ + krow_base + 8 * gg];
#pragma unroll
        for (int nt = 0; nt < 2; ++nt) {
          const int qcol = bt2 * 256 + wn * 64 + nt * 32 + l31;
#pragma unroll
          for (int r = 0; r < 16; r += 2) {
            const float vj0 = ((const float*)&vv[r >> 2])[r & 3];
            const float vj1 = ((const float*)&vv[r >> 2])[(r + 1) & 3];
            const bool m0 = vj0 > MASKED_SENTINEL;
            const bool m1 = vj1 > MASKED_SENTINEL;
            const float e0 =
                m0 ? __expf(fmaf((float)acci[mt][nt][r], KSC, vj0)) : 0.f;
            const float e1 =
                m1 ? __expf(fmaf((float)acci[mt][nt][r + 1], KSC, vj1)) : 0.f;
            zc[nt] += e0 + e1;
            const unsigned p = __builtin_amdgcn_cvt_pk_fp8_f32(e0, e1, 0, false);
            const int krow = krow_base + (r & 3) + 8 * (r >> 2);
            uint8_t* ad = OUT8 + ((size_t)cb * SEQ + krow) * (size_t)SEQ + qcol;
            if (m0) ad[0] = (uint8_t)p;            // masked rows never written
            if (m1) ad[SEQ] = (uint8_t)(p >> 8);
          }
        }
      }
#pragma unroll
      for (int nt = 0; nt < 2; ++nt) {
        float v = zc[nt];
        v += __shfl_xor(v, 32);
        zc[nt] = v;
      }
      float* red = (float*)(smem + 131072);   // [4 wm][256 q]
      if (lane < 32) {
#pragma unroll
        for (int nt = 0; nt < 2; ++nt)
          red[wm * 256 + wn * 64 + nt * 32 + l31] = zc[nt];
      }
      __syncthreads();
      if (t < 256)
        Zpart[((size_t)cb * 8 + at2) * SEQ + bt2 * 256 + t] =
            red[t] + red[256 + t] + red[512 + t] + red[768 + t];
    }
#pragma unroll
    for (int m = 0; m < 2; ++m)
#pragma unroll
      for (int n = 0; n < 2; ++n)
#pragma unroll
        for (int r = 0; r < 16; ++r) acci[m][n][r] = 0;
  };

  // prologue: tile 0 -> buf0
  stage_mat(Aof(0), smem, 0);
  stage_mat(Bb, smem + 32768, 0);
  WAIT_VM0();
  BAR();

  const int NI = 8 * TP;   // 8 K-steps of 128B per k-tile
#pragma unroll 1
  for (int ii = 0; ii < NI; ++ii) {
    const int p = ii & 1;
    const char* Al = smem + (p << 16);
    const char* Bl = smem + 32768 + (p << 16);
    // issue next-tile stage FIRST (max issue->drain distance)
    if (ii + 1 < NI) {
      stage_mat(Aof((ii + 1) >> 3), smem + ((p ^ 1) << 16), (ii + 1) & 7);
      stage_mat(Bb, smem + 32768 + ((p ^ 1) << 16), (ii + 1) & 7);
    }
    const int rA0 = (wm * 64 + l31) * 128, rA1 = (wm * 64 + 32 + l31) * 128;
    const int rB0 = (wn * 64 + l31) * 128, rB1 = (wn * 64 + 32 + l31) * 128;
#pragma unroll
    for (int ks = 0; ks < 4; ++ks) {
      const i32x4 af0 = *(const i32x4*)(Al + rA0 + pcI[ks]);
      const i32x4 af1 = *(const i32x4*)(Al + rA1 + pcI[ks]);
      const i32x4 bf0 = *(const i32x4*)(Bl + rB0 + pcI[ks]);
      const i32x4 bf1 = *(const i32x4*)(Bl + rB1 + pcI[ks]);
      __builtin_amdgcn_s_setprio(1);
      acci[0][0] = __builtin_amdgcn_mfma_i32_32x32x32_i8(af0, bf0, acci[0][0], 0, 0, 0);
      acci[0][1] = __builtin_amdgcn_mfma_i32_32x32x32_i8(af0, bf1, acci[0][1], 0, 0, 0);
      acci[1][0] = __builtin_amdgcn_mfma_i32_32x32x32_i8(af1, bf0, acci[1][0], 0, 0, 0);
      acci[1][1] = __builtin_amdgcn_mfma_i32_32x32x32_i8(af1, bf1, acci[1][1], 0, 0, 0);
      __builtin_amdgcn_s_setprio(0);
    }
    WAIT_LGKM0();   // all my ds-reads of buf p drained before crossing barrier
    WAIT_VM0();     // next tile landed
    if ((ii & 7) == 7) EPI(at2base + (ii >> 3));
    BAR();
  }
}

// ---------------------------------------------------------------------------
// fp32 [DMODEL][DMODEL] -> bf16 transposed; z selects (Wq->WqT, Wk->WkT)
__global__ void transpose_cvt_kernel(const float* __restrict__ inq,
                                     const float* __restrict__ ink,
                                     __hip_bfloat16* __restrict__ outq,
                                     __hip_bfloat16* __restrict__ outk) {
  __shared__ float tile[32][33];
  const float* in = blockIdx.z ? ink : inq;
  __hip_bfloat16* outp = blockIdx.z ? outk : outq;
  const int bx = blockIdx.x, by = blockIdx.y;
  const int tx = threadIdx.x & 31, ty = threadIdx.x >> 5;
#pragma unroll
  for (int r = 0; r < 32; r += 8)
    tile[ty + r][tx] = in[(size_t)(by * 32 + ty + r) * DMODEL + bx * 32 + tx];
  __syncthreads();
#pragma unroll
  for (int r = 0; r < 32; r += 8)
    outp[(size_t)(bx * 32 + ty + r) * DMODEL + by * 32 + tx] =
        __float2bfloat16(tile[tx][ty + r]);
}

// t2[d] = sum_e Wk[e][d]*bq[e]
__global__ __launch_bounds__(256)
void prep_t2_kernel(const __hip_bfloat16* __restrict__ WkT,
                    const float* __restrict__ bq, float* __restrict__ t2) {
  const int wave = threadIdx.x >> 6, lane = threadIdx.x & 63;
  const int d = blockIdx.x * 4 + wave;
  const short8* kr = (const short8*)(WkT + (size_t)d * DMODEL);
  float a2 = 0.f;
#pragma unroll
  for (int h = 0; h < 2; ++h) {
    const short8 kv = kr[lane * 2 + h];
    const int e0 = lane * 16 + h * 8;
#pragma unroll
    for (int i = 0; i < 8; ++i) a2 += bf2f(kv[i]) * bq[e0 + i];
  }
  a2 += __shfl_down(a2, 32); a2 += __shfl_down(a2, 16); a2 += __shfl_down(a2, 8);
  a2 += __shfl_down(a2, 4);  a2 += __shfl_down(a2, 2);  a2 += __shfl_down(a2, 1);
  if (lane == 0) t2[d] = a2;
}

// fused: x -> x8i (round(32x)) + vb'
__global__ __launch_bounds__(256)
void cvtv_kernel(const float* __restrict__ x, const float* __restrict__ t2,
                 const int* __restrict__ mask,
                 uint8_t* __restrict__ x8, float* __restrict__ vb) {
  const int wave = threadIdx.x >> 6, lane = threadIdx.x & 63;
  const size_t row = (size_t)blockIdx.x * 4 + wave;
  const float* xr = x + row * DMODEL;
  float a2 = 0.f;
#pragma unroll
  for (int p = 0; p < 4; ++p) {
    const int d = p * 256 + lane * 4;
    const float4 xv = *(const float4*)(xr + d);
    const float4 tv = *(const float4*)(t2 + d);
    a2 += xv.x * tv.x + xv.y * tv.y + xv.z * tv.z + xv.w * tv.w;
    uint32_t qp = (uint32_t)(qs8(xv.x, 32.f) & 0xff) |
                  ((uint32_t)(qs8(xv.y, 32.f) & 0xff) << 8) |
                  ((uint32_t)(qs8(xv.z, 32.f) & 0xff) << 16) |
                  ((uint32_t)(qs8(xv.w, 32.f) & 0xff) << 24);
    *(uint32_t*)(x8 + row * DMODEL + d) = qp;
  }
  a2 += __shfl_down(a2, 32); a2 += __shfl_down(a2, 16); a2 += __shfl_down(a2, 8);
  a2 += __shfl_down(a2, 4);  a2 += __shfl_down(a2, 2);  a2 += __shfl_down(a2, 1);
  if (lane == 0)
    vb[row] = mask[row] ? fmaf(a2, CS, -NEG4LN2) : -1e30f;
}

// ---------------------------------------------------------------------------
// fused zinv + passB + sumw. grid (nb, 32): cb FAST -> same XCD that wrote
// this batch's E rows (L2 hit). Masked rows skipped (w=0, E never read).
__global__ __launch_bounds__(256)
void wsolve_kernel(const uint8_t* __restrict__ E8,
                   const float* __restrict__ Zpart,
                   const int* __restrict__ mask,
                   float* __restrict__ wout, float* __restrict__ sumwp,
                   int b0) {
  __shared__ float rz[SEQ];
  __shared__ float sred[4];
  const int t = threadIdx.x, lane = t & 63, wave = t >> 6;
  const int cb = blockIdx.x, seg = blockIdx.y;
  for (int q = t; q < SEQ; q += 256) {
    float z = 0.f;
#pragma unroll
    for (int kt = 0; kt < 8; ++kt)
      z += Zpart[((size_t)cb * 8 + kt) * SEQ + q];
    rz[q] = (z > 0.f) ? (1.f / z) : 0.f;
  }
  __syncthreads();
  float4 rzv[4][2];
#pragma unroll
  for (int it = 0; it < 4; ++it) {
    rzv[it][0] = *(const float4*)&rz[it * 512 + lane * 8];
    rzv[it][1] = *(const float4*)&rz[it * 512 + lane * 8 + 4];
  }
  const int kbase = seg * 64 + wave * 16;
  float wsum = 0.f;
#pragma unroll 1
  for (int r = 0; r < 16; ++r) {
    const int k = kbase + r;
    if (!mask[(size_t)(b0 + cb) * SEQ + k]) {
      if (lane == 0) wout[(size_t)cb * SEQ + k] = 0.f;
      continue;
    }
    const uint2* Ep = (const uint2*)(E8 + ((size_t)cb * SEQ + k) * SEQ);
    float s = 0.f;
#pragma unroll
    for (int it = 0; it < 4; ++it) {
      const uint2 v = Ep[it * 64 + lane];
      const float* rzp = (const float*)&rzv[it][0];
      s += __builtin_amdgcn_cvt_f32_fp8(v.x, 0) * rzp[0];
      s += __builtin_amdgcn_cvt_f32_fp8(v.x, 1) * rzp[1];
      s += __builtin_amdgcn_cvt_f32_fp8(v.x, 2) * rzp[2];
      s += __builtin_amdgcn_cvt_f32_fp8(v.x, 3) * rzp[3];
      s += __builtin_amdgcn_cvt_f32_fp8(v.y, 0) * rzp[4];
      s += __builtin_amdgcn_cvt_f32_fp8(v.y, 1) * rzp[5];
      s += __builtin_amdgcn_cvt_f32_fp8(v.y, 2) * rzp[6];
      s += __builtin_amdgcn_cvt_f32_fp8(v.y, 3) * rzp[7];
    }
    s += __shfl_down(s, 32); s += __shfl_down(s, 16); s += __shfl_down(s, 8);
    s += __shfl_down(s, 4);  s += __shfl_down(s, 2);  s += __shfl_down(s, 1);
    if (lane == 0) { wout[(size_t)cb * SEQ + k] = s; wsum += s; }
  }
  if (lane == 0) sred[wave] = wsum;
  __syncthreads();
  if (t == 0)
    sumwp[(b0 + cb) * 32 + seg] = sred[0] + sred[1] + sred[2] + sred[3];
}

// wxp[kq][b][d] = (1/32) * sum_{k in chunk kq} w[k] * x8[b][k][d]
__global__ __launch_bounds__(256)
void wxpart_kernel(const uint8_t* __restrict__ x8,
                   const float* __restrict__ w,
                   float* __restrict__ wxp, int b0) {
  const int cb = blockIdx.y, kq = blockIdx.z;
  const int b = b0 + cb;
  const int d4 = threadIdx.x;
  const uint8_t* xb =
      x8 + ((size_t)b * SEQ + (size_t)kq * (SEQ / KSPLIT)) * DMODEL;
  const float* wb = w + (size_t)cb * SEQ + (size_t)kq * (SEQ / KSPLIT);
  float a0 = 0.f, a1 = 0.f, a2 = 0.f, a3 = 0.f;
#pragma unroll 4
  for (int k = 0; k < SEQ / KSPLIT; ++k) {
    const float wk = wb[k];
    const uint32_t pv = *(const uint32_t*)(xb + (size_t)k * DMODEL + d4 * 4);
    a0 += wk * (float)(int8_t)(pv & 0xff);
    a1 += wk * (float)(int8_t)((pv >> 8) & 0xff);
    a2 += wk * (float)(int8_t)((pv >> 16) & 0xff);
    a3 += wk * (float)(int8_t)(pv >> 24);
  }
  float4* o = (float4*)&wxp[((size_t)kq * NBATCH + b) * DMODEL + d4 * 4];
  *o = make_float4(a0 * 0.03125f, a1 * 0.03125f, a2 * 0.03125f, a3 * 0.03125f);
}

// out[b][e] = ( sum_d (sum_kq wxp) * Wv[e][d] + sumw[b]*bv[e] ) / SEQ
__global__ void final_kernel(const float* __restrict__ wxp,
                             const float* __restrict__ sumwp,
                             const float* __restrict__ Wv,
                             const float* __restrict__ bv,
                             float* __restrict__ out) {
  const int b = blockIdx.y, eg = blockIdx.x;
  const int wave = threadIdx.x >> 6, lane = threadIdx.x & 63;
  const int e = eg * 4 + wave;
  float acc = 0.f;
  for (int d = lane; d < DMODEL; d += 64) {
    float wx = 0.f;
#pragma unroll
    for (int kq = 0; kq < KSPLIT; ++kq)
      wx += wxp[((size_t)kq * NBATCH + b) * DMODEL + d];
    acc += wx * Wv[(size_t)e * DMODEL + d];
  }
  acc += __shfl_down(acc, 32); acc += __shfl_down(acc, 16);
  acc += __shfl_down(acc, 8);  acc += __shfl_down(acc, 4);
  acc += __shfl_down(acc, 2);  acc += __shfl_down(acc, 1);
  if (lane == 0) {
    float sw = 0.f;
#pragma unroll
    for (int i = 0; i < 32; ++i) sw += sumwp[b * 32 + i];
    out[(size_t)b * DMODEL + e] = (acc + sw * bv[e]) * (1.f / (float)SEQ);
  }
}

// ---------------------------------------------------------------------------
extern "C" void kernel_launch(void* const* d_in, const int* in_sizes, int n_in,
                              void* d_out, int out_size, void* d_ws, size_t ws_size,
                              hipStream_t stream) {
  const float* x  = (const float*)d_in[0];
  const int* mask = (const int*)d_in[1];
  const float* Wq = (const float*)d_in[2];
  const float* bq = (const float*)d_in[3];
  const float* Wk = (const float*)d_in[4];
  const float* bk = (const float*)d_in[5];
  const float* Wv = (const float*)d_in[6];
  const float* bv = (const float*)d_in[7];
  float* out = (float*)d_out;
  (void)bk;

  char* ws = (char*)d_ws;
  size_t off = 0;
  auto alloc = [&](size_t bytes) -> void* {
    void* p = ws + off;
    off += (bytes + 255) & ~(size_t)255;
    return p;
  };
  // ---- persistent ----
  uint8_t* Mt8 = (uint8_t*)alloc((size_t)DMODEL * DMODEL);
  __hip_bfloat16* WqT_bf = (__hip_bfloat16*)alloc((size_t)DMODEL * DMODEL * 2);
  __hip_bfloat16* WkT_bf = (__hip_bfloat16*)alloc((size_t)DMODEL * DMODEL * 2);
  float* wxp   = (float*)alloc((size_t)KSPLIT * NBATCH * DMODEL * 4);
  float* sumwp = (float*)alloc((size_t)NBATCH * 32 * 4);
  float* t2    = (float*)alloc((size_t)DMODEL * 4);
  uint8_t* x8i = (uint8_t*)alloc((size_t)NBATCH * SEQ * DMODEL);
  uint8_t* Y8i = (uint8_t*)alloc((size_t)NBATCH * SEQ * DMODEL);
  float* vb = (float*)alloc((size_t)NBATCH * SEQ * 4);
  const size_t fixed = off;

  // ---- per-chunk ----
  const size_t per_batch = (size_t)SEQ * SEQ      // E (fp8)
                         + (size_t)8 * SEQ * 4    // Zpart
                         + (size_t)SEQ * 4 + 8 * 256;
  long avail = (long)ws_size - (long)fixed;
  int NB = (int)(avail / (long)per_batch);
  if (NB < 1) NB = 1;
  if (NB > NBATCH) NB = NBATCH;
  while (NBATCH % NB) --NB;
  uint8_t* Ebuf = (uint8_t*)alloc((size_t)NB * SEQ * SEQ);
  float* Zpart = (float*)alloc((size_t)NB * 8 * SEQ * 4);
  float* wbuf  = (float*)alloc((size_t)NB * SEQ * 4);

  // ---- prep ----
  transpose_cvt_kernel<<<dim3(32, 32, 2), dim3(256), 0, stream>>>(
      Wq, Wk, WqT_bf, WkT_bf);
  // Mt8[d'][d] = round(1024 * sum_e WkT[d'][e]*WqT[d][e])
  gemmT_kernel<1><<<dim3(4, 4), dim3(512), 0, stream>>>(
      WqT_bf, WkT_bf, Mt8, DMODEL);
  prep_t2_kernel<<<dim3(256), dim3(256), 0, stream>>>(WkT_bf, bq, t2);
  cvtv_kernel<<<dim3(NBATCH * SEQ / 4), dim3(256), 0, stream>>>(
      x, t2, mask, x8i, vb);
  // Y8i = round( (x8 . Mt8) / 1024 ); 128 A-tiles, TP=2 -> 64 x 4 = 256 blocks
  i8gemm_kernel<0, 2><<<dim3(64, DMODEL / 256), dim3(1024), 0, stream>>>(
      x8i, Mt8, Y8i, nullptr, nullptr, 0);

  for (int b0 = 0; b0 < NBATCH; b0 += NB) {
    const int nb = NB;
    // passA: 3D grid (cb fast -> XCD pin; ktg; qt)
    i8gemm_kernel<1, 4><<<dim3(nb, 2, 8), dim3(1024), 0, stream>>>(
        x8i, Y8i, Ebuf, vb, Zpart, b0);
    wsolve_kernel<<<dim3(nb, 32), dim3(256), 0, stream>>>(
        Ebuf, Zpart, mask, wbuf, sumwp, b0);
    wxpart_kernel<<<dim3(1, nb, KSPLIT), dim3(256), 0, stream>>>(
        x8i, wbuf, wxp, b0);
  }
  final_kernel<<<dim3(DMODEL / 4, NBATCH), dim3(256), 0, stream>>>(
      wxp, sumwp, Wv, bv, out);
}